// Round 11
// baseline (259.637 us; speedup 1.0000x reference)
//
#include <hip/hip_runtime.h>
#include <hip/hip_bf16.h>

#define N_ 8
#define C_ 256
#define HW_ 4096
#define CNT_ (C_*HW_)

typedef __attribute__((ext_vector_type(8))) short bf16x8;
typedef __attribute__((ext_vector_type(4))) float f32x4;
typedef __attribute__((ext_vector_type(16))) float f32x16;
typedef __attribute__((ext_vector_type(4))) int i32x4;
typedef __attribute__((ext_vector_type(8))) int i32x8;

__device__ inline float exp2fast(float x){ return __builtin_amdgcn_exp2f(x); }

__device__ inline unsigned short f2bf(float f){
  union{float f; unsigned u;} v; v.f=f;
  unsigned r = v.u + 0x7fff + ((v.u>>16)&1);
  return (unsigned short)(r>>16);
}
__device__ inline float bf2f(unsigned short h){
  union{unsigned u; float f;} v; v.u = ((unsigned)h)<<16; return v.f;
}

__device__ inline f32x4 mfma16(bf16x8 a, bf16x8 b, f32x4 c){
  return __builtin_amdgcn_mfma_f32_16x16x32_bf16(a,b,c,0,0,0);
}
// MX-scaled fp8 K=64 MFMA, scales = 1.0 (E8M0 127), fmt 0 = fp8 e4m3
__device__ inline f32x16 mfma_mx(i32x8 a, i32x8 b, f32x16 c){
  return __builtin_amdgcn_mfma_scale_f32_32x32x64_f8f6f4(a, b, c, 0, 0, 0, 127, 0, 127);
}

__device__ inline i32x8 ld2x4(const char* p){
  i32x4 a = *(const i32x4*)p;
  i32x4 b = *(const i32x4*)(p+16);
  i32x8 r;
  r[0]=a[0]; r[1]=a[1]; r[2]=a[2]; r[3]=a[3];
  r[4]=b[0]; r[5]=b[1]; r[6]=b[2]; r[7]=b[3];
  return r;
}

#define GLL16(gp, lp) __builtin_amdgcn_global_load_lds( \
    (__attribute__((address_space(1))) void*)(gp), \
    (__attribute__((address_space(3))) void*)(lp), 16, 0, 0)

// ---------------- weight convert (fp32 -> bf16) ----------------
__global__ void k_cvt(const float* __restrict__ src, unsigned short* __restrict__ dst){
  int i = blockIdx.x*256 + threadIdx.x;
  dst[i] = f2bf(src[i]);
}

// ---------------- layernorm stats, stage 1 ----------------
__global__ void k_stats1(const float* __restrict__ x, float2* __restrict__ part){
  int n = blockIdx.x >> 8;
  int chunk = blockIdx.x & 255;
  const float4* p = (const float4*)(x + (size_t)n*CNT_ + (size_t)chunk*4096);
  int t = threadIdx.x;
  float s=0.f, s2=0.f;
  #pragma unroll
  for(int i=0;i<4;i++){
    float4 v = p[t + 256*i];
    s  += v.x+v.y+v.z+v.w;
    s2 += v.x*v.x+v.y*v.y+v.z*v.z+v.w*v.w;
  }
  #pragma unroll
  for(int o=32;o;o>>=1){ s += __shfl_down(s,o); s2 += __shfl_down(s2,o); }
  __shared__ float sh[4], sh2[4];
  int lane = t&63, wid = t>>6;
  if(lane==0){ sh[wid]=s; sh2[wid]=s2; }
  __syncthreads();
  if(t==0){
    float2 r; r.x = sh[0]+sh[1]+sh[2]+sh[3]; r.y = sh2[0]+sh2[1]+sh2[2]+sh2[3];
    part[blockIdx.x] = r;
  }
}

// ---------------- layernorm stats, stage 2 ----------------
__global__ void k_stats2(const float2* __restrict__ part, float2* __restrict__ stats){
  int n = blockIdx.x, t = threadIdx.x;
  float2 v = part[n*256 + t];
  float s = v.x, s2 = v.y;
  #pragma unroll
  for(int o=32;o;o>>=1){ s += __shfl_down(s,o); s2 += __shfl_down(s2,o); }
  __shared__ float sh[4], sh2[4];
  int lane = t&63, wid = t>>6;
  if(lane==0){ sh[wid]=s; sh2[wid]=s2; }
  __syncthreads();
  if(t==0){
    s = sh[0]+sh[1]+sh[2]+sh[3];
    s2 = sh2[0]+sh2[1]+sh2[2]+sh2[3];
    float mean = s * (1.f/(float)CNT_);
    float var  = s2 * (1.f/(float)CNT_) - mean*mean;
    float2 r; r.x = mean; r.y = rsqrtf(var + 1e-5f);
    stats[n] = r;
  }
}

// ---------------- normalize + transpose to NHWC bf16 ----------------
__global__ void k_norm(const float* __restrict__ x, const float* __restrict__ lnw,
                       const float* __restrict__ lnb, const float2* __restrict__ stats,
                       unsigned short* __restrict__ nx){
  __shared__ float tile[64][65];
  int n = blockIdx.z, c0 = blockIdx.y*64, p0 = blockIdx.x*64;
  float2 st = stats[n];
  float mu = st.x, rs = st.y;
  int t = threadIdx.x, col = t&63, rw = t>>6;
  #pragma unroll
  for(int pass=0; pass<16; pass++){
    int row = pass*4 + rw;
    size_t gi = (size_t)(c0+row)*HW_ + (p0+col);
    float v = x[(size_t)n*CNT_ + gi];
    tile[row][col] = (v - mu)*rs*lnw[gi] + lnb[gi];
  }
  __syncthreads();
  #pragma unroll
  for(int pass=0; pass<16; pass++){
    int prow = pass*4 + rw;
    nx[((size_t)n*HW_ + p0+prow)*C_ + c0 + col] = f2bf(tile[col][prow]);
  }
}

// ---------------- 128x128-tile B^T GEMM, LDS-staged (dbuf, issue-early) ----------------
// OUT_MODE: 0 = bf16, 1 = fp8-e4m3, 2 = fp32 + residual
__device__ inline void g2_stage(const char* A, const char* B, char* buf,
                                int w, int r8, int s8, int i0, int c0, int kb0){
  int sl = (s8 ^ (r8&7)) << 4;
  #pragma unroll
  for(int q=0;q<4;q++){
    int row = w*32 + q*8 + r8;
    GLL16(A + (size_t)(i0+row)*512 + kb0 + sl, buf + w*4096 + q*1024);
    GLL16(B + (size_t)(c0+row)*512 + kb0 + sl, buf + 16384 + w*4096 + q*1024);
  }
}

template<int BIAS_ROW, int OUT_MODE>
__global__ __launch_bounds__(256, 2) void k_gemm2(
    const unsigned short* __restrict__ Ab, long sA,
    const unsigned short* __restrict__ Bb, long sB,
    const float* __restrict__ bias, float scale,
    void* __restrict__ Outb, long sO, int ldo,
    float* __restrict__ foutb, const float* __restrict__ xres){
  __shared__ __align__(16) char lds[65536];
  int n = blockIdx.z;
  const char* A = (const char*)(Ab + (size_t)n*sA);
  const char* B = (const char*)(Bb + (size_t)n*sB);
  int t = threadIdx.x, w = t>>6, l = t&63;
  int wr = w>>1, wc = w&1, ri = l&15, kq = l>>4;
  int r8 = l>>3, s8 = l&7;
  int i0 = blockIdx.x*128, c0 = blockIdx.y*128;

  f32x4 acc[4][4];
  #pragma unroll
  for(int m=0;m<4;m++)
    #pragma unroll
    for(int nn=0;nn<4;nn++)
      #pragma unroll
      for(int r=0;r<4;r++) acc[m][nn][r] = 0.f;

  g2_stage(A, B, lds, w, r8, s8, i0, c0, 0);
  __syncthreads();

  for(int kt=0; kt<4; ++kt){
    char* buf = lds + (kt&1)*32768;
    if (kt < 3) g2_stage(A, B, lds + ((kt&1)^1)*32768, w, r8, s8, i0, c0, (kt+1)*128);
    __builtin_amdgcn_s_setprio(1);
    #pragma unroll
    for(int kc=0;kc<2;kc++){
      bf16x8 af[4], bfv[4];
      #pragma unroll
      for(int m=0;m<4;m++){
        int row = wr*64 + m*16 + ri;
        af[m] = *(const bf16x8*)(buf + row*128 + ((((kc<<2)|kq) ^ (row&7))<<4));
      }
      #pragma unroll
      for(int nn=0;nn<4;nn++){
        int row = wc*64 + nn*16 + ri;
        bfv[nn] = *(const bf16x8*)(buf + 16384 + row*128 + ((((kc<<2)|kq) ^ (row&7))<<4));
      }
      #pragma unroll
      for(int m=0;m<4;m++)
        #pragma unroll
        for(int nn=0;nn<4;nn++)
          acc[m][nn] = mfma16(af[m], bfv[nn], acc[m][nn]);
    }
    __builtin_amdgcn_s_setprio(0);
    __syncthreads();
  }

  if (OUT_MODE == 2){
    float* fout = foutb + (size_t)n*sO;
    const float* xr = xres + (size_t)n*sO;
    #pragma unroll
    for(int m=0;m<4;m++){
      #pragma unroll
      for(int nn=0;nn<4;nn++){
        #pragma unroll
        for(int r=0;r<4;r++){
          int row = i0 + wr*64 + m*16 + kq*4 + r;
          int col = c0 + wc*64 + nn*16 + ri;
          size_t idx = (size_t)row*ldo + col;
          fout[idx] = acc[m][nn][r] + bias[row] + xr[idx];
        }
      }
    }
  } else if (OUT_MODE == 1){
    unsigned char* O8 = (unsigned char*)Outb + (size_t)n*sO;
    #pragma unroll
    for(int m=0;m<4;m++){
      #pragma unroll
      for(int nn=0;nn<4;nn++){
        #pragma unroll
        for(int r=0;r<4;r++){
          int row = i0 + wr*64 + m*16 + kq*4 + r;
          int col = c0 + wc*64 + nn*16 + ri;
          float d = (acc[m][nn][r] + bias[BIAS_ROW ? row : col])*scale;
          unsigned u;
          asm("v_cvt_pk_fp8_f32 %0, %1, %2" : "=v"(u) : "v"(d), "v"(0.f));
          O8[(size_t)row*ldo + col] = (unsigned char)(u & 0xff);
        }
      }
    }
  } else {
    unsigned short* O = (unsigned short*)Outb + (size_t)n*sO;
    #pragma unroll
    for(int m=0;m<4;m++){
      #pragma unroll
      for(int nn=0;nn<4;nn++){
        #pragma unroll
        for(int r=0;r<4;r++){
          int row = i0 + wr*64 + m*16 + kq*4 + r;
          int col = c0 + wc*64 + nn*16 + ri;
          float d = (acc[m][nn][r] + bias[BIAS_ROW ? row : col])*scale;
          O[(size_t)row*ldo + col] = f2bf(d);
        }
      }
    }
  }
}

// ---------------- flash attention: all-fp8 MX (K=64), BJ=64, dbuf, issue-early ----------
// 512 blocks x 256 threads. Block = (batch, q-tile of 128, j-half of 2048).
// Per buf: K fp8 [64 rows][256B] (16 KB, linear byte-copy) + V fp8 [256 d][64 j] (16 KB).
// 64 KB LDS -> 2 blocks/CU. QK: 8x mfma_scale_32x32x64 (Sa/Sb dual tiles).
// PV: P packed fp8 via cvt_pk_fp8 + 4 permlane32_swap; 8x mfma_scale_32x32x64.
__device__ inline void stage_KV_mx(const char* kb, const char* vb, char* buf,
                                   int w, int l, int j0){
  #pragma unroll
  for(int k=0;k<4;k++){
    int g = w*4 + k;
    GLL16(kb + (size_t)j0*256 + g*1024 + l*16, buf + g*1024);
  }
  #pragma unroll
  for(int k=0;k<4;k++){
    int g = w*4 + k;
    int idx = g*1024 + l*16;
    GLL16(vb + (size_t)(idx>>6)*4096 + j0 + (idx&63), buf + 16384 + g*1024);
  }
}

__global__ __launch_bounds__(256, 2) void k_attn8(const unsigned char* __restrict__ qt,
                                                  const unsigned char* __restrict__ kt,
                                                  const unsigned char* __restrict__ vv,
                                                  unsigned short* __restrict__ pO0,
                                                  unsigned short* __restrict__ pO1,
                                                  float2* __restrict__ pml){
  __shared__ __align__(16) char lds[65536];     // 2 x (16 KB K + 16 KB V)
  int t = threadIdx.x, w = t>>6, l = t&63, hi = l>>5, lo5 = l&31;
  int nb = blockIdx.x & 7, rem = blockIdx.x >> 3;
  int qb = rem >> 1, jh = rem & 1;
  int q0 = qb*128 + w*32;
  const char* kb = (const char*)(kt + (size_t)nb*HW_*C_);
  const char* vb = (const char*)(vv + (size_t)nb*(size_t)CNT_);
  const char* qp = (const char*)(qt + (size_t)nb*HW_*C_);
  int jbase = jh*2048;

  // Q fragments fp8: 4 d-blocks x 32B = 32 VGPR
  i32x8 qfr[4];
  #pragma unroll
  for(int db=0; db<4; db++)
    qfr[db] = ld2x4(qp + (size_t)(q0+lo5)*256 + db*64 + hi*32);

  f32x16 o[8];
  #pragma unroll
  for(int dt=0;dt<8;dt++){
    #pragma unroll
    for(int r=0;r<16;r++) o[dt][r]=0.f;
  }
  float m = -1e30f, lsum = 0.f;

  stage_KV_mx(kb, vb, lds, w, l, jbase);
  __syncthreads();

  for(int it=0; it<32; ++it){
    char* bufc = lds + (it&1)*32768;
    if (it < 31) stage_KV_mx(kb, vb, lds + ((it&1)^1)*32768, w, l, jbase + (it+1)*64);

    // QK^T: Sa = j[0,32), Sb = j[32,64); lane q = lo5, k = d (4 blocks of 64)
    f32x16 Sa, Sb;
    #pragma unroll
    for(int r=0;r<16;r++){ Sa[r]=0.f; Sb[r]=0.f; }
    __builtin_amdgcn_s_setprio(1);
    #pragma unroll
    for(int db=0; db<4; db++){
      i32x8 ka  = ld2x4(bufc + lo5*256      + db*64 + hi*32);
      i32x8 kb2 = ld2x4(bufc + (32+lo5)*256 + db*64 + hi*32);
      Sa = mfma_mx(ka,  qfr[db], Sa);
      Sb = mfma_mx(kb2, qfr[db], Sb);
    }
    __builtin_amdgcn_s_setprio(0);

    // joint online softmax (base-2; Q,K pre-scaled by sqrt(log2e/16))
    float mm[8];
    #pragma unroll
    for(int r=0;r<8;r++) mm[r] = fmaxf(fmaxf(Sa[r],Sa[r+8]), fmaxf(Sb[r],Sb[r+8]));
    mm[0]=fmaxf(mm[0],mm[4]); mm[1]=fmaxf(mm[1],mm[5]);
    mm[2]=fmaxf(mm[2],mm[6]); mm[3]=fmaxf(mm[3],mm[7]);
    float mx = fmaxf(fmaxf(mm[0],mm[1]), fmaxf(mm[2],mm[3]));
    { float mA = mx, mB = mx;
      asm("v_permlane32_swap_b32 %0, %1" : "+v"(mA), "+v"(mB));
      mx = fmaxf(mA, mB); }
    if (!__all(mx <= m + 8.f)){     // THR=8: P <= 256 < fp8 e4m3 max 448
      float mn = fmaxf(m, mx);
      float al = exp2fast(m - mn);
      lsum *= al;
      #pragma unroll
      for(int dt=0;dt<8;dt++) o[dt] = o[dt] * al;
      m = mn;
    }
    // exp (in place) + row-sum
    float rs = 0.f;
    #pragma unroll
    for(int r=0;r<16;r++){
      Sa[r] = exp2fast(Sa[r]-m); rs += Sa[r];
      Sb[r] = exp2fast(Sb[r]-m); rs += Sb[r];
    }
    { float rA = rs, rB = rs;
      asm("v_permlane32_swap_b32 %0, %1" : "+v"(rA), "+v"(rB));
      lsum += rA + rB; }

    // pack P to fp8 words: A_w (tile a), B_w (tile b), w=0..3 covers j-bytes 4w..4w+3
    unsigned Aw[4], Bw[4];
    #pragma unroll
    for(int w4=0; w4<4; w4++){
      unsigned ua, ub;
      asm("v_cvt_pk_fp8_f32 %0, %1, %2" : "=v"(ua) : "v"(Sa[4*w4]), "v"(Sa[4*w4+1]));
      asm("v_cvt_pk_fp8_f32 %0, %1, %2 op_sel:[0,0,1]" : "+v"(ua) : "v"(Sa[4*w4+2]), "v"(Sa[4*w4+3]));
      asm("v_cvt_pk_fp8_f32 %0, %1, %2" : "=v"(ub) : "v"(Sb[4*w4]), "v"(Sb[4*w4+1]));
      asm("v_cvt_pk_fp8_f32 %0, %1, %2 op_sel:[0,0,1]" : "+v"(ub) : "v"(Sb[4*w4+2]), "v"(Sb[4*w4+3]));
      Aw[w4] = ua; Bw[w4] = ub;
    }
    // cross-half exchange: after swap, op[2w]=Aw, op[2w+1]=Bw for ALL lanes
    #pragma unroll
    for(int w4=0; w4<4; w4++)
      asm("v_permlane32_swap_b32 %0, %1" : "+v"(Aw[w4]), "+v"(Bw[w4]));
    i32x8 P;
    P[0]=Aw[0]; P[1]=Bw[0]; P[2]=Aw[1]; P[3]=Bw[1];
    P[4]=Aw[2]; P[5]=Bw[2]; P[6]=Aw[3]; P[7]=Bw[3];

    // PV: O^T[d][q] += V[d][j]*P[q][j], K=64 per MFMA
    __builtin_amdgcn_s_setprio(1);
    #pragma unroll
    for(int dt=0;dt<8;dt++){
      i32x8 vf = ld2x4(bufc + 16384 + (dt*32+lo5)*64 + hi*32);
      o[dt] = mfma_mx(vf, P, o[dt]);
    }
    __builtin_amdgcn_s_setprio(0);
    __syncthreads();
  }

  unsigned short* pb = (jh ? pO1 : pO0) + ((size_t)nb*HW_ + q0 + lo5)*C_;
  #pragma unroll
  for(int dt=0;dt<8;dt++){
    #pragma unroll
    for(int g=0;g<4;g++){
      int d0 = dt*32 + g*8 + hi*4;
      unsigned short h0 = f2bf(o[dt][4*g]);
      unsigned short h1 = f2bf(o[dt][4*g+1]);
      unsigned short h2 = f2bf(o[dt][4*g+2]);
      unsigned short h3 = f2bf(o[dt][4*g+3]);
      uint2 uo; uo.x = (unsigned)h0 | ((unsigned)h1<<16);
      uo.y = (unsigned)h2 | ((unsigned)h3<<16);
      *(uint2*)(pb + d0) = uo;
    }
  }
  if (l < 32){
    float2 ml; ml.x = m; ml.y = lsum;
    pml[(size_t)jh*32768 + (size_t)nb*HW_ + q0 + lo5] = ml;
  }
}

// ---------------- merge the two j-half partials (in place into pO0 = rest) ----------------
__global__ void k_merge(unsigned short* __restrict__ pO0,
                        const unsigned short* __restrict__ pO1,
                        const float2* __restrict__ pml){
  int t = threadIdx.x;
  int row = blockIdx.x*8 + (t>>5);
  int dn = t & 31;
  float2 ml0 = pml[row], ml1 = pml[32768 + row];
  float mN = fmaxf(ml0.x, ml1.x);
  float a0 = exp2fast(ml0.x - mN), a1 = exp2fast(ml1.x - mN);
  float inv = 1.f/(a0*ml0.y + a1*ml1.y);
  float s0 = a0*inv, s1 = a1*inv;
  size_t off = (size_t)row*256 + dn*8;
  uint4 u0 = *(const uint4*)(pO0 + off);
  uint4 u1 = *(const uint4*)(pO1 + off);
  unsigned r[4];
  unsigned w0[4] = {u0.x, u0.y, u0.z, u0.w};
  unsigned w1[4] = {u1.x, u1.y, u1.z, u1.w};
  #pragma unroll
  for(int q=0;q<4;q++){
    float lo = s0*bf2f((unsigned short)(w0[q]&0xffff)) + s1*bf2f((unsigned short)(w1[q]&0xffff));
    float hi = s0*bf2f((unsigned short)(w0[q]>>16))    + s1*bf2f((unsigned short)(w1[q]>>16));
    r[q] = (unsigned)f2bf(lo) | ((unsigned)f2bf(hi)<<16);
  }
  uint4 ru; ru.x=r[0]; ru.y=r[1]; ru.z=r[2]; ru.w=r[3];
  *(uint4*)(pO0 + off) = ru;
}

extern "C" void kernel_launch(void* const* d_in, const int* in_sizes, int n_in,
                              void* d_out, int out_size, void* d_ws, size_t ws_size,
                              hipStream_t stream) {
  const float* x   = (const float*)d_in[0];
  const float* lnw = (const float*)d_in[1];
  const float* lnb = (const float*)d_in[2];
  const float* wq  = (const float*)d_in[3];
  const float* bq  = (const float*)d_in[4];
  const float* wk  = (const float*)d_in[5];
  const float* bk  = (const float*)d_in[6];
  const float* wv  = (const float*)d_in[7];
  const float* bv  = (const float*)d_in[8];
  const float* wo  = (const float*)d_in[9];
  const float* bo  = (const float*)d_in[10];
  float* out = (float*)d_out;

  uintptr_t base = (uintptr_t)d_ws;
  float2* part  = (float2*)base;
  float2* stats = (float2*)(base + 16384);
  unsigned short* wqb = (unsigned short*)(base + 16448);
  unsigned short* wkb = wqb + 65536;
  unsigned short* wvb = wqb + 2*65536;
  unsigned short* wob = wqb + 3*65536;
  unsigned short* nx  = wqb + 4*65536;
  const size_t TEN = (size_t)N_*HW_*C_;
  unsigned short* qtb = nx + TEN;       // fp8 Q (8 MB used of 16)
  unsigned short* ktb = qtb + TEN;      // fp8 K
  unsigned short* vvb = ktb + TEN;      // fp8 V [dim][seq]
  unsigned short* pO1 = vvb + TEN;
  float2* pml = (float2*)(pO1 + TEN);
  unsigned short* rest = nx;            // = pO0, merged in place

  k_cvt<<<dim3(256),256,0,stream>>>(wq, wqb);
  k_cvt<<<dim3(256),256,0,stream>>>(wk, wkb);
  k_cvt<<<dim3(256),256,0,stream>>>(wv, wvb);
  k_cvt<<<dim3(256),256,0,stream>>>(wo, wob);

  k_stats1<<<dim3(2048),256,0,stream>>>(x, part);
  k_stats2<<<dim3(8),256,0,stream>>>(part, stats);
  k_norm<<<dim3(64,4,8),256,0,stream>>>(x, lnw, lnb, stats, nx);

  // Q,K fp8 scaled by sqrt(log2(e)/16); V fp8 [dim][seq]
  k_gemm2<0,1><<<dim3(32,2,8),256,0,stream>>>(nx, (long)(HW_*C_), wqb, 0L, bq, 0.3002807f,
                                              qtb, (long)(HW_*C_), C_, nullptr, nullptr);
  k_gemm2<0,1><<<dim3(32,2,8),256,0,stream>>>(nx, (long)(HW_*C_), wkb, 0L, bk, 0.3002807f,
                                              ktb, (long)(HW_*C_), C_, nullptr, nullptr);
  k_gemm2<1,1><<<dim3(2,32,8),256,0,stream>>>(wvb, 0L, nx, (long)(HW_*C_), bv, 1.0f,
                                              vvb, (long)(CNT_), HW_, nullptr, nullptr);

  k_attn8<<<dim3(512),256,0,stream>>>((const unsigned char*)qtb, (const unsigned char*)ktb,
                                      (const unsigned char*)vvb, rest, pO1, pml);
  k_merge<<<dim3(4096),256,0,stream>>>(rest, pO1, pml);

  k_gemm2<1,2><<<dim3(2,32,8),256,0,stream>>>(wob, 0L, rest, (long)(HW_*C_), bo, 1.0f,
                                              nullptr, (long)(CNT_), HW_, out, x);
}

// Round 12
// 173.294 us; speedup vs baseline: 1.4982x; 1.4982x over previous
//
#include <hip/hip_runtime.h>
#include <hip/hip_bf16.h>

#define N_ 8
#define C_ 256
#define HW_ 4096
#define CNT_ (C_*HW_)

typedef __attribute__((ext_vector_type(8))) short bf16x8;
typedef __attribute__((ext_vector_type(4))) float f32x4;
typedef __attribute__((ext_vector_type(16))) float f32x16;
typedef __attribute__((ext_vector_type(4))) int i32x4;
typedef __attribute__((ext_vector_type(8))) int i32x8;

__device__ inline float exp2fast(float x){ return __builtin_amdgcn_exp2f(x); }

__device__ inline unsigned short f2bf(float f){
  union{float f; unsigned u;} v; v.f=f;
  unsigned r = v.u + 0x7fff + ((v.u>>16)&1);
  return (unsigned short)(r>>16);
}
__device__ inline float bf2f(unsigned short h){
  union{unsigned u; float f;} v; v.u = ((unsigned)h)<<16; return v.f;
}

__device__ inline f32x4 mfma16(bf16x8 a, bf16x8 b, f32x4 c){
  return __builtin_amdgcn_mfma_f32_16x16x32_bf16(a,b,c,0,0,0);
}
// MX-scaled fp8 K=64 MFMA, scales = 1.0 (E8M0 127), fmt 0 = fp8 e4m3
__device__ inline f32x16 mfma_mx(i32x8 a, i32x8 b, f32x16 c){
  return __builtin_amdgcn_mfma_scale_f32_32x32x64_f8f6f4(a, b, c, 0, 0, 0, 127, 0, 127);
}

__device__ inline i32x8 ld2x4(const char* p){
  i32x4 a = *(const i32x4*)p;
  i32x4 b = *(const i32x4*)(p+16);
  i32x8 r;
  r[0]=a[0]; r[1]=a[1]; r[2]=a[2]; r[3]=a[3];
  r[4]=b[0]; r[5]=b[1]; r[6]=b[2]; r[7]=b[3];
  return r;
}

#define GLL16(gp, lp) __builtin_amdgcn_global_load_lds( \
    (__attribute__((address_space(1))) void*)(gp), \
    (__attribute__((address_space(3))) void*)(lp), 16, 0, 0)

// ---------------- weight convert (fp32 -> bf16) ----------------
__global__ void k_cvt(const float* __restrict__ src, unsigned short* __restrict__ dst){
  int i = blockIdx.x*256 + threadIdx.x;
  dst[i] = f2bf(src[i]);
}

// ---------------- layernorm stats, stage 1 ----------------
__global__ void k_stats1(const float* __restrict__ x, float2* __restrict__ part){
  int n = blockIdx.x >> 8;
  int chunk = blockIdx.x & 255;
  const float4* p = (const float4*)(x + (size_t)n*CNT_ + (size_t)chunk*4096);
  int t = threadIdx.x;
  float s=0.f, s2=0.f;
  #pragma unroll
  for(int i=0;i<4;i++){
    float4 v = p[t + 256*i];
    s  += v.x+v.y+v.z+v.w;
    s2 += v.x*v.x+v.y*v.y+v.z*v.z+v.w*v.w;
  }
  #pragma unroll
  for(int o=32;o;o>>=1){ s += __shfl_down(s,o); s2 += __shfl_down(s2,o); }
  __shared__ float sh[4], sh2[4];
  int lane = t&63, wid = t>>6;
  if(lane==0){ sh[wid]=s; sh2[wid]=s2; }
  __syncthreads();
  if(t==0){
    float2 r; r.x = sh[0]+sh[1]+sh[2]+sh[3]; r.y = sh2[0]+sh2[1]+sh2[2]+sh2[3];
    part[blockIdx.x] = r;
  }
}

// ---------------- layernorm stats, stage 2 ----------------
__global__ void k_stats2(const float2* __restrict__ part, float2* __restrict__ stats){
  int n = blockIdx.x, t = threadIdx.x;
  float2 v = part[n*256 + t];
  float s = v.x, s2 = v.y;
  #pragma unroll
  for(int o=32;o;o>>=1){ s += __shfl_down(s,o); s2 += __shfl_down(s2,o); }
  __shared__ float sh[4], sh2[4];
  int lane = t&63, wid = t>>6;
  if(lane==0){ sh[wid]=s; sh2[wid]=s2; }
  __syncthreads();
  if(t==0){
    s = sh[0]+sh[1]+sh[2]+sh[3];
    s2 = sh2[0]+sh2[1]+sh2[2]+sh2[3];
    float mean = s * (1.f/(float)CNT_);
    float var  = s2 * (1.f/(float)CNT_) - mean*mean;
    float2 r; r.x = mean; r.y = rsqrtf(var + 1e-5f);
    stats[n] = r;
  }
}

// ---------------- normalize + transpose to NHWC bf16 ----------------
__global__ void k_norm(const float* __restrict__ x, const float* __restrict__ lnw,
                       const float* __restrict__ lnb, const float2* __restrict__ stats,
                       unsigned short* __restrict__ nx){
  __shared__ float tile[64][65];
  int n = blockIdx.z, c0 = blockIdx.y*64, p0 = blockIdx.x*64;
  float2 st = stats[n];
  float mu = st.x, rs = st.y;
  int t = threadIdx.x, col = t&63, rw = t>>6;
  #pragma unroll
  for(int pass=0; pass<16; pass++){
    int row = pass*4 + rw;
    size_t gi = (size_t)(c0+row)*HW_ + (p0+col);
    float v = x[(size_t)n*CNT_ + gi];
    tile[row][col] = (v - mu)*rs*lnw[gi] + lnb[gi];
  }
  __syncthreads();
  #pragma unroll
  for(int pass=0; pass<16; pass++){
    int prow = pass*4 + rw;
    nx[((size_t)n*HW_ + p0+prow)*C_ + c0 + col] = f2bf(tile[col][prow]);
  }
}

// ---------------- 128x128-tile B^T GEMM, LDS-staged (dbuf, issue-early) ----------------
// OUT_MODE: 0 = bf16, 1 = fp8-e4m3, 2 = fp32 + residual
__device__ inline void g2_stage(const char* A, const char* B, char* buf,
                                int w, int r8, int s8, int i0, int c0, int kb0){
  int sl = (s8 ^ (r8&7)) << 4;
  #pragma unroll
  for(int q=0;q<4;q++){
    int row = w*32 + q*8 + r8;
    GLL16(A + (size_t)(i0+row)*512 + kb0 + sl, buf + w*4096 + q*1024);
    GLL16(B + (size_t)(c0+row)*512 + kb0 + sl, buf + 16384 + w*4096 + q*1024);
  }
}

template<int BIAS_ROW, int OUT_MODE>
__global__ __launch_bounds__(256, 2) void k_gemm2(
    const unsigned short* __restrict__ Ab, long sA,
    const unsigned short* __restrict__ Bb, long sB,
    const float* __restrict__ bias, float scale,
    void* __restrict__ Outb, long sO, int ldo,
    float* __restrict__ foutb, const float* __restrict__ xres){
  __shared__ __align__(16) char lds[65536];
  int n = blockIdx.z;
  const char* A = (const char*)(Ab + (size_t)n*sA);
  const char* B = (const char*)(Bb + (size_t)n*sB);
  int t = threadIdx.x, w = t>>6, l = t&63;
  int wr = w>>1, wc = w&1, ri = l&15, kq = l>>4;
  int r8 = l>>3, s8 = l&7;
  int i0 = blockIdx.x*128, c0 = blockIdx.y*128;

  f32x4 acc[4][4];
  #pragma unroll
  for(int m=0;m<4;m++)
    #pragma unroll
    for(int nn=0;nn<4;nn++)
      #pragma unroll
      for(int r=0;r<4;r++) acc[m][nn][r] = 0.f;

  g2_stage(A, B, lds, w, r8, s8, i0, c0, 0);
  __syncthreads();

  for(int kt=0; kt<4; ++kt){
    char* buf = lds + (kt&1)*32768;
    if (kt < 3) g2_stage(A, B, lds + ((kt&1)^1)*32768, w, r8, s8, i0, c0, (kt+1)*128);
    __builtin_amdgcn_s_setprio(1);
    #pragma unroll
    for(int kc=0;kc<2;kc++){
      bf16x8 af[4], bfv[4];
      #pragma unroll
      for(int m=0;m<4;m++){
        int row = wr*64 + m*16 + ri;
        af[m] = *(const bf16x8*)(buf + row*128 + ((((kc<<2)|kq) ^ (row&7))<<4));
      }
      #pragma unroll
      for(int nn=0;nn<4;nn++){
        int row = wc*64 + nn*16 + ri;
        bfv[nn] = *(const bf16x8*)(buf + 16384 + row*128 + ((((kc<<2)|kq) ^ (row&7))<<4));
      }
      #pragma unroll
      for(int m=0;m<4;m++)
        #pragma unroll
        for(int nn=0;nn<4;nn++)
          acc[m][nn] = mfma16(af[m], bfv[nn], acc[m][nn]);
    }
    __builtin_amdgcn_s_setprio(0);
    __syncthreads();
  }

  if (OUT_MODE == 2){
    float* fout = foutb + (size_t)n*sO;
    const float* xr = xres + (size_t)n*sO;
    #pragma unroll
    for(int m=0;m<4;m++){
      #pragma unroll
      for(int nn=0;nn<4;nn++){
        #pragma unroll
        for(int r=0;r<4;r++){
          int row = i0 + wr*64 + m*16 + kq*4 + r;
          int col = c0 + wc*64 + nn*16 + ri;
          size_t idx = (size_t)row*ldo + col;
          fout[idx] = acc[m][nn][r] + bias[row] + xr[idx];
        }
      }
    }
  } else if (OUT_MODE == 1){
    unsigned char* O8 = (unsigned char*)Outb + (size_t)n*sO;
    #pragma unroll
    for(int m=0;m<4;m++){
      #pragma unroll
      for(int nn=0;nn<4;nn++){
        #pragma unroll
        for(int r=0;r<4;r++){
          int row = i0 + wr*64 + m*16 + kq*4 + r;
          int col = c0 + wc*64 + nn*16 + ri;
          float d = (acc[m][nn][r] + bias[BIAS_ROW ? row : col])*scale;
          unsigned u;
          asm("v_cvt_pk_fp8_f32 %0, %1, %2" : "=v"(u) : "v"(d), "v"(0.f));
          O8[(size_t)row*ldo + col] = (unsigned char)(u & 0xff);
        }
      }
    }
  } else {
    unsigned short* O = (unsigned short*)Outb + (size_t)n*sO;
    #pragma unroll
    for(int m=0;m<4;m++){
      #pragma unroll
      for(int nn=0;nn<4;nn++){
        #pragma unroll
        for(int r=0;r<4;r++){
          int row = i0 + wr*64 + m*16 + kq*4 + r;
          int col = c0 + wc*64 + nn*16 + ri;
          float d = (acc[m][nn][r] + bias[BIAS_ROW ? row : col])*scale;
          O[(size_t)row*ldo + col] = f2bf(d);
        }
      }
    }
  }
}

// ---------------- flash attention: all-fp8 MX (K=64), BJ=64, swizzled LDS ----------
// 512 blocks x 256 threads. Block = (batch, q-tile of 128, j-half of 2048).
// Per buf: K fp8 [64 rows][256B] with 32B-slot XOR (slot p holds d-slice p^(row&7), 16 KB)
//        + V fp8 [256 d][80B: 64 j-data + 16 dup-pad] (20 KB) = 36 KB; dbuf = 72 KB.
__device__ inline void stage_KV_mx(const char* kb, const char* vb, char* buf,
                                   int w, int l, int j0){
  // K: 16 gll; lane l of gll g lands at byte g*1024+l*16 -> row g*4+(l>>4), 16B idx i=l&15.
  // Physical 32B slot (i>>1) must hold source slice (i>>1)^(row&7).
  #pragma unroll
  for(int k=0;k<4;k++){
    int g = w*4 + k;
    int row = g*4 + (l>>4);
    int i = l & 15;
    int sp = (((i>>1) ^ (row&7))<<5) + ((i&1)<<4);
    GLL16(kb + (size_t)(j0+row)*256 + sp, buf + g*1024);
  }
  // V: 20 gll; rows of 80B = 5 16B-slots (slot 4 duplicates slot 0 as pad)
  #pragma unroll
  for(int k=0;k<5;k++){
    int g = w*5 + k;
    int c = g*64 + l;
    int d = c/5; int sg = c - d*5; sg = (sg==4)?0:sg;
    GLL16(vb + (size_t)d*HW_ + j0 + sg*16, buf + 16384 + g*1024);
  }
}

__global__ __launch_bounds__(256, 2) void k_attn8(const unsigned char* __restrict__ qt,
                                                  const unsigned char* __restrict__ kt,
                                                  const unsigned char* __restrict__ vv,
                                                  unsigned short* __restrict__ pO0,
                                                  unsigned short* __restrict__ pO1,
                                                  float2* __restrict__ pml){
  __shared__ __align__(16) char lds[73728];     // 2 x (16 KB K + 20 KB V)
  int t = threadIdx.x, w = t>>6, l = t&63, hi = l>>5, lo5 = l&31;
  int nb = blockIdx.x & 7, rem = blockIdx.x >> 3;
  int qb = rem >> 1, jh = rem & 1;
  int q0 = qb*128 + w*32;
  const char* kb = (const char*)(kt + (size_t)nb*HW_*C_);
  const char* vb = (const char*)(vv + (size_t)nb*(size_t)CNT_);
  const char* qp = (const char*)(qt + (size_t)nb*HW_*C_);
  int jbase = jh*2048;

  // Q fragments fp8: 4 d-blocks x 32B = 32 VGPR
  i32x8 qfr[4];
  #pragma unroll
  for(int db=0; db<4; db++)
    qfr[db] = ld2x4(qp + (size_t)(q0+lo5)*256 + db*64 + hi*32);

  f32x16 o[8];
  #pragma unroll
  for(int dt=0;dt<8;dt++){
    #pragma unroll
    for(int r=0;r<16;r++) o[dt][r]=0.f;
  }
  float m = -1e30f, lsum = 0.f;

  stage_KV_mx(kb, vb, lds, w, l, jbase);
  __syncthreads();

  for(int it=0; it<32; ++it){
    char* bufc = lds + (it&1)*36864;
    if (it < 31) stage_KV_mx(kb, vb, lds + ((it&1)^1)*36864, w, l, jbase + (it+1)*64);

    // QK^T: Sa = j[0,32), Sb = j[32,64); lane q = lo5, k-slice = hi*32 of d-block db
    f32x16 Sa, Sb;
    #pragma unroll
    for(int r=0;r<16;r++){ Sa[r]=0.f; Sb[r]=0.f; }
    __builtin_amdgcn_s_setprio(1);
    #pragma unroll
    for(int db=0; db<4; db++){
      int sl = ((db*2+hi) ^ (lo5&7))<<5;
      i32x8 ka  = ld2x4(bufc + lo5*256      + sl);
      i32x8 kb2 = ld2x4(bufc + (32+lo5)*256 + sl);
      Sa = mfma_mx(ka,  qfr[db], Sa);
      Sb = mfma_mx(kb2, qfr[db], Sb);
    }
    __builtin_amdgcn_s_setprio(0);

    // joint online softmax (base-2; Q,K pre-scaled by sqrt(log2e/16))
    float mm[8];
    #pragma unroll
    for(int r=0;r<8;r++) mm[r] = fmaxf(fmaxf(Sa[r],Sa[r+8]), fmaxf(Sb[r],Sb[r+8]));
    mm[0]=fmaxf(mm[0],mm[4]); mm[1]=fmaxf(mm[1],mm[5]);
    mm[2]=fmaxf(mm[2],mm[6]); mm[3]=fmaxf(mm[3],mm[7]);
    float mx = fmaxf(fmaxf(mm[0],mm[1]), fmaxf(mm[2],mm[3]));
    { float mA = mx, mB = mx;
      asm("v_permlane32_swap_b32 %0, %1" : "+v"(mA), "+v"(mB));
      mx = fmaxf(mA, mB); }
    if (!__all(mx <= m + 8.f)){     // THR=8: P <= 256 < fp8 e4m3 max 448
      float mn = fmaxf(m, mx);
      float al = exp2fast(m - mn);
      lsum *= al;
      #pragma unroll
      for(int dt=0;dt<8;dt++) o[dt] = o[dt] * al;
      m = mn;
    }
    // exp (in place) + row-sum
    float rs = 0.f;
    #pragma unroll
    for(int r=0;r<16;r++){
      Sa[r] = exp2fast(Sa[r]-m); rs += Sa[r];
      Sb[r] = exp2fast(Sb[r]-m); rs += Sb[r];
    }
    { float rA = rs, rB = rs;
      asm("v_permlane32_swap_b32 %0, %1" : "+v"(rA), "+v"(rB));
      lsum += rA + rB; }

    // pack P to fp8 words: A_w (tile a), B_w (tile b), w=0..3 covers j-bytes 4w..4w+3
    unsigned Aw[4], Bw[4];
    #pragma unroll
    for(int w4=0; w4<4; w4++){
      unsigned ua, ub;
      asm("v_cvt_pk_fp8_f32 %0, %1, %2" : "=v"(ua) : "v"(Sa[4*w4]), "v"(Sa[4*w4+1]));
      asm("v_cvt_pk_fp8_f32 %0, %1, %2 op_sel:[0,0,1]" : "+v"(ua) : "v"(Sa[4*w4+2]), "v"(Sa[4*w4+3]));
      asm("v_cvt_pk_fp8_f32 %0, %1, %2" : "=v"(ub) : "v"(Sb[4*w4]), "v"(Sb[4*w4+1]));
      asm("v_cvt_pk_fp8_f32 %0, %1, %2 op_sel:[0,0,1]" : "+v"(ub) : "v"(Sb[4*w4+2]), "v"(Sb[4*w4+3]));
      Aw[w4] = ua; Bw[w4] = ub;
    }
    // cross-half exchange: after swap, op[2w]=Aw, op[2w+1]=Bw for ALL lanes
    #pragma unroll
    for(int w4=0; w4<4; w4++)
      asm("v_permlane32_swap_b32 %0, %1" : "+v"(Aw[w4]), "+v"(Bw[w4]));
    i32x8 P;
    P[0]=Aw[0]; P[1]=Bw[0]; P[2]=Aw[1]; P[3]=Bw[1];
    P[4]=Aw[2]; P[5]=Bw[2]; P[6]=Aw[3]; P[7]=Bw[3];

    // PV: O^T[d][q] += V[d][j]*P[q][j], K=64 per MFMA
    __builtin_amdgcn_s_setprio(1);
    #pragma unroll
    for(int dt=0;dt<8;dt++){
      i32x8 vf = ld2x4(bufc + 16384 + (dt*32+lo5)*80 + hi*32);
      o[dt] = mfma_mx(vf, P, o[dt]);
    }
    __builtin_amdgcn_s_setprio(0);
    __syncthreads();
  }

  unsigned short* pb = (jh ? pO1 : pO0) + ((size_t)nb*HW_ + q0 + lo5)*C_;
  #pragma unroll
  for(int dt=0;dt<8;dt++){
    #pragma unroll
    for(int g=0;g<4;g++){
      int d0 = dt*32 + g*8 + hi*4;
      unsigned short h0 = f2bf(o[dt][4*g]);
      unsigned short h1 = f2bf(o[dt][4*g+1]);
      unsigned short h2 = f2bf(o[dt][4*g+2]);
      unsigned short h3 = f2bf(o[dt][4*g+3]);
      uint2 uo; uo.x = (unsigned)h0 | ((unsigned)h1<<16);
      uo.y = (unsigned)h2 | ((unsigned)h3<<16);
      *(uint2*)(pb + d0) = uo;
    }
  }
  if (l < 32){
    float2 ml; ml.x = m; ml.y = lsum;
    pml[(size_t)jh*32768 + (size_t)nb*HW_ + q0 + lo5] = ml;
  }
}

// ---------------- merge the two j-half partials (in place into pO0 = rest) ----------------
__global__ void k_merge(unsigned short* __restrict__ pO0,
                        const unsigned short* __restrict__ pO1,
                        const float2* __restrict__ pml){
  int t = threadIdx.x;
  int row = blockIdx.x*8 + (t>>5);
  int dn = t & 31;
  float2 ml0 = pml[row], ml1 = pml[32768 + row];
  float mN = fmaxf(ml0.x, ml1.x);
  float a0 = exp2fast(ml0.x - mN), a1 = exp2fast(ml1.x - mN);
  float inv = 1.f/(a0*ml0.y + a1*ml1.y);
  float s0 = a0*inv, s1 = a1*inv;
  size_t off = (size_t)row*256 + dn*8;
  uint4 u0 = *(const uint4*)(pO0 + off);
  uint4 u1 = *(const uint4*)(pO1 + off);
  unsigned r[4];
  unsigned w0[4] = {u0.x, u0.y, u0.z, u0.w};
  unsigned w1[4] = {u1.x, u1.y, u1.z, u1.w};
  #pragma unroll
  for(int q=0;q<4;q++){
    float lo = s0*bf2f((unsigned short)(w0[q]&0xffff)) + s1*bf2f((unsigned short)(w1[q]&0xffff));
    float hi = s0*bf2f((unsigned short)(w0[q]>>16))    + s1*bf2f((unsigned short)(w1[q]>>16));
    r[q] = (unsigned)f2bf(lo) | ((unsigned)f2bf(hi)<<16);
  }
  uint4 ru; ru.x=r[0]; ru.y=r[1]; ru.z=r[2]; ru.w=r[3];
  *(uint4*)(pO0 + off) = ru;
}

extern "C" void kernel_launch(void* const* d_in, const int* in_sizes, int n_in,
                              void* d_out, int out_size, void* d_ws, size_t ws_size,
                              hipStream_t stream) {
  const float* x   = (const float*)d_in[0];
  const float* lnw = (const float*)d_in[1];
  const float* lnb = (const float*)d_in[2];
  const float* wq  = (const float*)d_in[3];
  const float* bq  = (const float*)d_in[4];
  const float* wk  = (const float*)d_in[5];
  const float* bk  = (const float*)d_in[6];
  const float* wv  = (const float*)d_in[7];
  const float* bv  = (const float*)d_in[8];
  const float* wo  = (const float*)d_in[9];
  const float* bo  = (const float*)d_in[10];
  float* out = (float*)d_out;

  uintptr_t base = (uintptr_t)d_ws;
  float2* part  = (float2*)base;
  float2* stats = (float2*)(base + 16384);
  unsigned short* wqb = (unsigned short*)(base + 16448);
  unsigned short* wkb = wqb + 65536;
  unsigned short* wvb = wqb + 2*65536;
  unsigned short* wob = wqb + 3*65536;
  unsigned short* nx  = wqb + 4*65536;
  const size_t TEN = (size_t)N_*HW_*C_;
  unsigned short* qtb = nx + TEN;       // fp8 Q (8 MB used of 16)
  unsigned short* ktb = qtb + TEN;      // fp8 K
  unsigned short* vvb = ktb + TEN;      // fp8 V [dim][seq]
  unsigned short* pO1 = vvb + TEN;
  float2* pml = (float2*)(pO1 + TEN);
  unsigned short* rest = nx;            // = pO0, merged in place

  k_cvt<<<dim3(256),256,0,stream>>>(wq, wqb);
  k_cvt<<<dim3(256),256,0,stream>>>(wk, wkb);
  k_cvt<<<dim3(256),256,0,stream>>>(wv, wvb);
  k_cvt<<<dim3(256),256,0,stream>>>(wo, wob);

  k_stats1<<<dim3(2048),256,0,stream>>>(x, part);
  k_stats2<<<dim3(8),256,0,stream>>>(part, stats);
  k_norm<<<dim3(64,4,8),256,0,stream>>>(x, lnw, lnb, stats, nx);

  // Q,K fp8 scaled by sqrt(log2(e)/16); V fp8 [dim][seq]
  k_gemm2<0,1><<<dim3(32,2,8),256,0,stream>>>(nx, (long)(HW_*C_), wqb, 0L, bq, 0.3002807f,
                                              qtb, (long)(HW_*C_), C_, nullptr, nullptr);
  k_gemm2<0,1><<<dim3(32,2,8),256,0,stream>>>(nx, (long)(HW_*C_), wkb, 0L, bk, 0.3002807f,
                                              ktb, (long)(HW_*C_), C_, nullptr, nullptr);
  k_gemm2<1,1><<<dim3(2,32,8),256,0,stream>>>(wvb, 0L, nx, (long)(HW_*C_), bv, 1.0f,
                                              vvb, (long)(CNT_), HW_, nullptr, nullptr);

  k_attn8<<<dim3(512),256,0,stream>>>((const unsigned char*)qtb, (const unsigned char*)ktb,
                                      (const unsigned char*)vvb, rest, pO1, pml);
  k_merge<<<dim3(4096),256,0,stream>>>(rest, pO1, pml);

  k_gemm2<1,2><<<dim3(2,32,8),256,0,stream>>>(wob, 0L, rest, (long)(HW_*C_), bo, 1.0f,
                                              nullptr, (long)(CNT_), HW_, out, x);
}

// Round 13
// 163.813 us; speedup vs baseline: 1.5850x; 1.0579x over previous
//
#include <hip/hip_runtime.h>
#include <hip/hip_bf16.h>

#define N_ 8
#define C_ 256
#define HW_ 4096
#define CNT_ (C_*HW_)

typedef __attribute__((ext_vector_type(8))) short bf16x8;
typedef __attribute__((ext_vector_type(4))) float f32x4;
typedef __attribute__((ext_vector_type(16))) float f32x16;
typedef __attribute__((ext_vector_type(4))) int i32x4;
typedef __attribute__((ext_vector_type(8))) int i32x8;

__device__ inline float exp2fast(float x){ return __builtin_amdgcn_exp2f(x); }

__device__ inline unsigned short f2bf(float f){
  union{float f; unsigned u;} v; v.f=f;
  unsigned r = v.u + 0x7fff + ((v.u>>16)&1);
  return (unsigned short)(r>>16);
}
__device__ inline float bf2f(unsigned short h){
  union{unsigned u; float f;} v; v.u = ((unsigned)h)<<16; return v.f;
}

__device__ inline f32x4 mfma16(bf16x8 a, bf16x8 b, f32x4 c){
  return __builtin_amdgcn_mfma_f32_16x16x32_bf16(a,b,c,0,0,0);
}
// MX-scaled fp8 K=64 MFMA, scales = 1.0 (E8M0 127), fmt 0 = fp8 e4m3
__device__ inline f32x16 mfma_mx(i32x8 a, i32x8 b, f32x16 c){
  return __builtin_amdgcn_mfma_scale_f32_32x32x64_f8f6f4(a, b, c, 0, 0, 0, 127, 0, 127);
}

__device__ inline i32x8 ld2x4(const char* p){
  i32x4 a = *(const i32x4*)p;
  i32x4 b = *(const i32x4*)(p+16);
  i32x8 r;
  r[0]=a[0]; r[1]=a[1]; r[2]=a[2]; r[3]=a[3];
  r[4]=b[0]; r[5]=b[1]; r[6]=b[2]; r[7]=b[3];
  return r;
}

#define GLL16(gp, lp) __builtin_amdgcn_global_load_lds( \
    (__attribute__((address_space(1))) void*)(gp), \
    (__attribute__((address_space(3))) void*)(lp), 16, 0, 0)

// ---------------- weight convert, all 4 matrices in one launch ----------------
__global__ void k_cvtall(const float* __restrict__ s0, const float* __restrict__ s1,
                         const float* __restrict__ s2, const float* __restrict__ s3,
                         unsigned short* __restrict__ dst){
  int i = blockIdx.x*256 + threadIdx.x;
  const float* s = (i < 65536) ? s0 : (i < 131072) ? s1 : (i < 196608) ? s2 : s3;
  dst[i] = f2bf(s[i & 65535]);
}

// ---------------- layernorm stats, stage 1 ----------------
__global__ void k_stats1(const float* __restrict__ x, float2* __restrict__ part){
  int n = blockIdx.x >> 8;
  int chunk = blockIdx.x & 255;
  const float4* p = (const float4*)(x + (size_t)n*CNT_ + (size_t)chunk*4096);
  int t = threadIdx.x;
  float s=0.f, s2=0.f;
  #pragma unroll
  for(int i=0;i<4;i++){
    float4 v = p[t + 256*i];
    s  += v.x+v.y+v.z+v.w;
    s2 += v.x*v.x+v.y*v.y+v.z*v.z+v.w*v.w;
  }
  #pragma unroll
  for(int o=32;o;o>>=1){ s += __shfl_down(s,o); s2 += __shfl_down(s2,o); }
  __shared__ float sh[4], sh2[4];
  int lane = t&63, wid = t>>6;
  if(lane==0){ sh[wid]=s; sh2[wid]=s2; }
  __syncthreads();
  if(t==0){
    float2 r; r.x = sh[0]+sh[1]+sh[2]+sh[3]; r.y = sh2[0]+sh2[1]+sh2[2]+sh2[3];
    part[blockIdx.x] = r;
  }
}

// ---------------- normalize + transpose to NHWC bf16 (stats stage-2 inlined) ----------------
__global__ void k_norm(const float* __restrict__ x, const float* __restrict__ lnw,
                       const float* __restrict__ lnb, const float2* __restrict__ part,
                       unsigned short* __restrict__ nx){
  __shared__ float tile[64][65];
  __shared__ float2 stsh;
  int n = blockIdx.z, c0 = blockIdx.y*64, p0 = blockIdx.x*64;
  int t = threadIdx.x, col = t&63, rw = t>>6;
  // inline stage-2 reduction over the 256 partials of batch n
  {
    float2 v = part[n*256 + t];
    float s = v.x, s2 = v.y;
    #pragma unroll
    for(int o=32;o;o>>=1){ s += __shfl_down(s,o); s2 += __shfl_down(s2,o); }
    __shared__ float sh[4], sh2[4];
    int lane = t&63, wid = t>>6;
    if(lane==0){ sh[wid]=s; sh2[wid]=s2; }
    __syncthreads();
    if(t==0){
      s = sh[0]+sh[1]+sh[2]+sh[3];
      s2 = sh2[0]+sh2[1]+sh2[2]+sh2[3];
      float mean = s * (1.f/(float)CNT_);
      float var  = s2 * (1.f/(float)CNT_) - mean*mean;
      float2 r; r.x = mean; r.y = rsqrtf(var + 1e-5f);
      stsh = r;
    }
    __syncthreads();
  }
  float mu = stsh.x, rs = stsh.y;
  #pragma unroll
  for(int pass=0; pass<16; pass++){
    int row = pass*4 + rw;
    size_t gi = (size_t)(c0+row)*HW_ + (p0+col);
    float v = x[(size_t)n*CNT_ + gi];
    tile[row][col] = (v - mu)*rs*lnw[gi] + lnb[gi];
  }
  __syncthreads();
  #pragma unroll
  for(int pass=0; pass<16; pass++){
    int prow = pass*4 + rw;
    nx[((size_t)n*HW_ + p0+prow)*C_ + c0 + col] = f2bf(tile[col][prow]);
  }
}

// ---------------- 128x128-tile B^T GEMM, LDS-staged (dbuf, issue-early) ----------------
// OUT_MODE: 0 = bf16, 1 = fp8-e4m3
__device__ inline void g2_stage(const char* A, const char* B, char* buf,
                                int w, int r8, int s8, int i0, int c0, int kb0){
  int sl = (s8 ^ (r8&7)) << 4;
  #pragma unroll
  for(int q=0;q<4;q++){
    int row = w*32 + q*8 + r8;
    GLL16(A + (size_t)(i0+row)*512 + kb0 + sl, buf + w*4096 + q*1024);
    GLL16(B + (size_t)(c0+row)*512 + kb0 + sl, buf + 16384 + w*4096 + q*1024);
  }
}

template<int BIAS_ROW, int OUT_MODE>
__global__ __launch_bounds__(256, 2) void k_gemm2(
    const unsigned short* __restrict__ Ab, long sA,
    const unsigned short* __restrict__ Bb, long sB,
    const float* __restrict__ bias, float scale,
    void* __restrict__ Outb, long sO, int ldo){
  __shared__ __align__(16) char lds[65536];
  int n = blockIdx.z;
  const char* A = (const char*)(Ab + (size_t)n*sA);
  const char* B = (const char*)(Bb + (size_t)n*sB);
  int t = threadIdx.x, w = t>>6, l = t&63;
  int wr = w>>1, wc = w&1, ri = l&15, kq = l>>4;
  int r8 = l>>3, s8 = l&7;
  int i0 = blockIdx.x*128, c0 = blockIdx.y*128;

  f32x4 acc[4][4];
  #pragma unroll
  for(int m=0;m<4;m++)
    #pragma unroll
    for(int nn=0;nn<4;nn++)
      #pragma unroll
      for(int r=0;r<4;r++) acc[m][nn][r] = 0.f;

  g2_stage(A, B, lds, w, r8, s8, i0, c0, 0);
  __syncthreads();

  for(int kt=0; kt<4; ++kt){
    char* buf = lds + (kt&1)*32768;
    if (kt < 3) g2_stage(A, B, lds + ((kt&1)^1)*32768, w, r8, s8, i0, c0, (kt+1)*128);
    __builtin_amdgcn_s_setprio(1);
    #pragma unroll
    for(int kc=0;kc<2;kc++){
      bf16x8 af[4], bfv[4];
      #pragma unroll
      for(int m=0;m<4;m++){
        int row = wr*64 + m*16 + ri;
        af[m] = *(const bf16x8*)(buf + row*128 + ((((kc<<2)|kq) ^ (row&7))<<4));
      }
      #pragma unroll
      for(int nn=0;nn<4;nn++){
        int row = wc*64 + nn*16 + ri;
        bfv[nn] = *(const bf16x8*)(buf + 16384 + row*128 + ((((kc<<2)|kq) ^ (row&7))<<4));
      }
      #pragma unroll
      for(int m=0;m<4;m++)
        #pragma unroll
        for(int nn=0;nn<4;nn++)
          acc[m][nn] = mfma16(af[m], bfv[nn], acc[m][nn]);
    }
    __builtin_amdgcn_s_setprio(0);
    __syncthreads();
  }

  if (OUT_MODE == 1){
    unsigned char* O8 = (unsigned char*)Outb + (size_t)n*sO;
    #pragma unroll
    for(int m=0;m<4;m++){
      #pragma unroll
      for(int nn=0;nn<4;nn++){
        #pragma unroll
        for(int r=0;r<4;r++){
          int row = i0 + wr*64 + m*16 + kq*4 + r;
          int col = c0 + wc*64 + nn*16 + ri;
          float d = (acc[m][nn][r] + bias[BIAS_ROW ? row : col])*scale;
          unsigned u;
          asm("v_cvt_pk_fp8_f32 %0, %1, %2" : "=v"(u) : "v"(d), "v"(0.f));
          O8[(size_t)row*ldo + col] = (unsigned char)(u & 0xff);
        }
      }
    }
  } else {
    unsigned short* O = (unsigned short*)Outb + (size_t)n*sO;
    #pragma unroll
    for(int m=0;m<4;m++){
      #pragma unroll
      for(int nn=0;nn<4;nn++){
        #pragma unroll
        for(int r=0;r<4;r++){
          int row = i0 + wr*64 + m*16 + kq*4 + r;
          int col = c0 + wc*64 + nn*16 + ri;
          float d = (acc[m][nn][r] + bias[BIAS_ROW ? row : col])*scale;
          O[(size_t)row*ldo + col] = f2bf(d);
        }
      }
    }
  }
}

// ---------------- output projection with inline j-half merge + residual ----------------
// out[n][c][p] = x + bo[c] + sum_d wo[c][d] * (s0*pO0[p][d] + s1*pO1[p][d])
// A = wo (GLL-staged, swizzled); B = merged-on-the-fly (reg loads -> combine -> ds_write).
__global__ __launch_bounds__(256, 2) void k_outproj2(
    const unsigned short* __restrict__ wob,
    const unsigned short* __restrict__ pO0, const unsigned short* __restrict__ pO1,
    const float2* __restrict__ pml,
    const float* __restrict__ bo, const float* __restrict__ x,
    float* __restrict__ out){
  __shared__ __align__(16) char lds[65536];
  int n = blockIdx.z;
  const char* A = (const char*)wob;
  const char* B0 = (const char*)(pO0 + (size_t)n*HW_*C_);
  const char* B1 = (const char*)(pO1 + (size_t)n*HW_*C_);
  int t = threadIdx.x, w = t>>6, l = t&63;
  int wr = w>>1, wc = w&1, ri = l&15, kq = l>>4;
  int r8 = l>>3, s8 = l&7;
  int i0 = blockIdx.x*128, c0 = blockIdx.y*128;
  int sl = (s8 ^ (r8&7)) << 4;

  // per-thread merge scales for the 4 staged B rows (fixed across k-tiles)
  float s0v[4], s1v[4];
  #pragma unroll
  for(int q=0;q<4;q++){
    int row = c0 + w*32 + q*8 + r8;
    float2 ml0 = pml[(size_t)n*HW_ + row];
    float2 ml1 = pml[(size_t)N_*HW_ + (size_t)n*HW_ + row];
    float mN = fmaxf(ml0.x, ml1.x);
    float a0 = exp2fast(ml0.x - mN), a1 = exp2fast(ml1.x - mN);
    float inv = 1.f/(a0*ml0.y + a1*ml1.y);
    s0v[q] = a0*inv; s1v[q] = a1*inv;
  }

  f32x4 acc[4][4];
  #pragma unroll
  for(int m=0;m<4;m++)
    #pragma unroll
    for(int nn=0;nn<4;nn++)
      #pragma unroll
      for(int r=0;r<4;r++) acc[m][nn][r] = 0.f;

  uint4 bl0[4], bl1[4];
  // prologue: stage tile 0 (A via GLL, B via regs), write B, sync
  #pragma unroll
  for(int q=0;q<4;q++){
    int row = w*32 + q*8 + r8;
    GLL16(A + (size_t)(i0+row)*512 + sl, lds + w*4096 + q*1024);
    bl0[q] = *(const uint4*)(B0 + (size_t)(c0+row)*512 + sl);
    bl1[q] = *(const uint4*)(B1 + (size_t)(c0+row)*512 + sl);
  }
  #pragma unroll
  for(int q=0;q<4;q++){
    unsigned w0[4] = {bl0[q].x, bl0[q].y, bl0[q].z, bl0[q].w};
    unsigned w1[4] = {bl1[q].x, bl1[q].y, bl1[q].z, bl1[q].w};
    uint4 rw;
    unsigned rr[4];
    #pragma unroll
    for(int j=0;j<4;j++){
      float lo = s0v[q]*bf2f((unsigned short)(w0[j]&0xffff)) + s1v[q]*bf2f((unsigned short)(w1[j]&0xffff));
      float hi = s0v[q]*bf2f((unsigned short)(w0[j]>>16))    + s1v[q]*bf2f((unsigned short)(w1[j]>>16));
      rr[j] = (unsigned)f2bf(lo) | ((unsigned)f2bf(hi)<<16);
    }
    rw.x=rr[0]; rw.y=rr[1]; rw.z=rr[2]; rw.w=rr[3];
    *(uint4*)(lds + 16384 + w*4096 + q*1024 + l*16) = rw;
  }
  __syncthreads();

  for(int kt=0; kt<4; ++kt){
    char* buf  = lds + (kt&1)*32768;
    char* nbuf = lds + ((kt&1)^1)*32768;
    if (kt < 3){
      int kb0 = (kt+1)*128;
      #pragma unroll
      for(int q=0;q<4;q++){
        int row = w*32 + q*8 + r8;
        GLL16(A + (size_t)(i0+row)*512 + kb0 + sl, nbuf + w*4096 + q*1024);
        bl0[q] = *(const uint4*)(B0 + (size_t)(c0+row)*512 + kb0 + sl);
        bl1[q] = *(const uint4*)(B1 + (size_t)(c0+row)*512 + kb0 + sl);
      }
    }
    __builtin_amdgcn_s_setprio(1);
    #pragma unroll
    for(int kc=0;kc<2;kc++){
      bf16x8 af[4], bfv[4];
      #pragma unroll
      for(int m=0;m<4;m++){
        int row = wr*64 + m*16 + ri;
        af[m] = *(const bf16x8*)(buf + row*128 + ((((kc<<2)|kq) ^ (row&7))<<4));
      }
      #pragma unroll
      for(int nn=0;nn<4;nn++){
        int row = wc*64 + nn*16 + ri;
        bfv[nn] = *(const bf16x8*)(buf + 16384 + row*128 + ((((kc<<2)|kq) ^ (row&7))<<4));
      }
      #pragma unroll
      for(int m=0;m<4;m++)
        #pragma unroll
        for(int nn=0;nn<4;nn++)
          acc[m][nn] = mfma16(af[m], bfv[nn], acc[m][nn]);
    }
    __builtin_amdgcn_s_setprio(0);
    if (kt < 3){
      #pragma unroll
      for(int q=0;q<4;q++){
        unsigned w0[4] = {bl0[q].x, bl0[q].y, bl0[q].z, bl0[q].w};
        unsigned w1[4] = {bl1[q].x, bl1[q].y, bl1[q].z, bl1[q].w};
        unsigned rr[4];
        #pragma unroll
        for(int j=0;j<4;j++){
          float lo = s0v[q]*bf2f((unsigned short)(w0[j]&0xffff)) + s1v[q]*bf2f((unsigned short)(w1[j]&0xffff));
          float hi = s0v[q]*bf2f((unsigned short)(w0[j]>>16))    + s1v[q]*bf2f((unsigned short)(w1[j]>>16));
          rr[j] = (unsigned)f2bf(lo) | ((unsigned)f2bf(hi)<<16);
        }
        uint4 rw; rw.x=rr[0]; rw.y=rr[1]; rw.z=rr[2]; rw.w=rr[3];
        *(uint4*)(nbuf + 16384 + w*4096 + q*1024 + l*16) = rw;
      }
    }
    __syncthreads();
  }

  const float* xr = x + (size_t)n*CNT_;
  float* fout = out + (size_t)n*CNT_;
  #pragma unroll
  for(int m=0;m<4;m++){
    #pragma unroll
    for(int nn=0;nn<4;nn++){
      #pragma unroll
      for(int r=0;r<4;r++){
        int row = i0 + wr*64 + m*16 + kq*4 + r;
        int col = c0 + wc*64 + nn*16 + ri;
        size_t idx = (size_t)row*HW_ + col;
        fout[idx] = acc[m][nn][r] + bo[row] + xr[idx];
      }
    }
  }
}

// ---------------- flash attention: all-fp8 MX (K=64), BJ=64, swizzled LDS ----------
__device__ inline void stage_KV_mx(const char* kb, const char* vb, char* buf,
                                   int w, int l, int j0){
  #pragma unroll
  for(int k=0;k<4;k++){
    int g = w*4 + k;
    int row = g*4 + (l>>4);
    int i = l & 15;
    int sp = (((i>>1) ^ (row&7))<<5) + ((i&1)<<4);
    GLL16(kb + (size_t)(j0+row)*256 + sp, buf + g*1024);
  }
  #pragma unroll
  for(int k=0;k<5;k++){
    int g = w*5 + k;
    int c = g*64 + l;
    int d = c/5; int sg = c - d*5; sg = (sg==4)?0:sg;
    GLL16(vb + (size_t)d*HW_ + j0 + sg*16, buf + 16384 + g*1024);
  }
}

__global__ __launch_bounds__(256, 2) void k_attn8(const unsigned char* __restrict__ qt,
                                                  const unsigned char* __restrict__ kt,
                                                  const unsigned char* __restrict__ vv,
                                                  unsigned short* __restrict__ pO0,
                                                  unsigned short* __restrict__ pO1,
                                                  float2* __restrict__ pml){
  __shared__ __align__(16) char lds[73728];     // 2 x (16 KB K + 20 KB V)
  int t = threadIdx.x, w = t>>6, l = t&63, hi = l>>5, lo5 = l&31;
  int nb = blockIdx.x & 7, rem = blockIdx.x >> 3;
  int qb = rem >> 1, jh = rem & 1;
  int q0 = qb*128 + w*32;
  const char* kb = (const char*)(kt + (size_t)nb*HW_*C_);
  const char* vb = (const char*)(vv + (size_t)nb*(size_t)CNT_);
  const char* qp = (const char*)(qt + (size_t)nb*HW_*C_);
  int jbase = jh*2048;

  i32x8 qfr[4];
  #pragma unroll
  for(int db=0; db<4; db++)
    qfr[db] = ld2x4(qp + (size_t)(q0+lo5)*256 + db*64 + hi*32);

  f32x16 o[8];
  #pragma unroll
  for(int dt=0;dt<8;dt++){
    #pragma unroll
    for(int r=0;r<16;r++) o[dt][r]=0.f;
  }
  float m = -1e30f, lsum = 0.f;

  stage_KV_mx(kb, vb, lds, w, l, jbase);
  __syncthreads();

  for(int it=0; it<32; ++it){
    char* bufc = lds + (it&1)*36864;
    if (it < 31) stage_KV_mx(kb, vb, lds + ((it&1)^1)*36864, w, l, jbase + (it+1)*64);

    f32x16 Sa, Sb;
    #pragma unroll
    for(int r=0;r<16;r++){ Sa[r]=0.f; Sb[r]=0.f; }
    __builtin_amdgcn_s_setprio(1);
    #pragma unroll
    for(int db=0; db<4; db++){
      int sl = ((db*2+hi) ^ (lo5&7))<<5;
      i32x8 ka  = ld2x4(bufc + lo5*256      + sl);
      i32x8 kb2 = ld2x4(bufc + (32+lo5)*256 + sl);
      Sa = mfma_mx(ka,  qfr[db], Sa);
      Sb = mfma_mx(kb2, qfr[db], Sb);
    }
    __builtin_amdgcn_s_setprio(0);

    float mm[8];
    #pragma unroll
    for(int r=0;r<8;r++) mm[r] = fmaxf(fmaxf(Sa[r],Sa[r+8]), fmaxf(Sb[r],Sb[r+8]));
    mm[0]=fmaxf(mm[0],mm[4]); mm[1]=fmaxf(mm[1],mm[5]);
    mm[2]=fmaxf(mm[2],mm[6]); mm[3]=fmaxf(mm[3],mm[7]);
    float mx = fmaxf(fmaxf(mm[0],mm[1]), fmaxf(mm[2],mm[3]));
    { float mA = mx, mB = mx;
      asm("v_permlane32_swap_b32 %0, %1" : "+v"(mA), "+v"(mB));
      mx = fmaxf(mA, mB); }
    if (!__all(mx <= m + 8.f)){     // THR=8: P <= 256 < fp8 e4m3 max 448
      float mn = fmaxf(m, mx);
      float al = exp2fast(m - mn);
      lsum *= al;
      #pragma unroll
      for(int dt=0;dt<8;dt++) o[dt] = o[dt] * al;
      m = mn;
    }
    float rs = 0.f;
    #pragma unroll
    for(int r=0;r<16;r++){
      Sa[r] = exp2fast(Sa[r]-m); rs += Sa[r];
      Sb[r] = exp2fast(Sb[r]-m); rs += Sb[r];
    }
    { float rA = rs, rB = rs;
      asm("v_permlane32_swap_b32 %0, %1" : "+v"(rA), "+v"(rB));
      lsum += rA + rB; }

    unsigned Aw[4], Bw[4];
    #pragma unroll
    for(int w4=0; w4<4; w4++){
      unsigned ua, ub;
      asm("v_cvt_pk_fp8_f32 %0, %1, %2" : "=v"(ua) : "v"(Sa[4*w4]), "v"(Sa[4*w4+1]));
      asm("v_cvt_pk_fp8_f32 %0, %1, %2 op_sel:[0,0,1]" : "+v"(ua) : "v"(Sa[4*w4+2]), "v"(Sa[4*w4+3]));
      asm("v_cvt_pk_fp8_f32 %0, %1, %2" : "=v"(ub) : "v"(Sb[4*w4]), "v"(Sb[4*w4+1]));
      asm("v_cvt_pk_fp8_f32 %0, %1, %2 op_sel:[0,0,1]" : "+v"(ub) : "v"(Sb[4*w4+2]), "v"(Sb[4*w4+3]));
      Aw[w4] = ua; Bw[w4] = ub;
    }
    #pragma unroll
    for(int w4=0; w4<4; w4++)
      asm("v_permlane32_swap_b32 %0, %1" : "+v"(Aw[w4]), "+v"(Bw[w4]));
    i32x8 P;
    P[0]=Aw[0]; P[1]=Bw[0]; P[2]=Aw[1]; P[3]=Bw[1];
    P[4]=Aw[2]; P[5]=Bw[2]; P[6]=Aw[3]; P[7]=Bw[3];

    __builtin_amdgcn_s_setprio(1);
    #pragma unroll
    for(int dt=0;dt<8;dt++){
      i32x8 vf = ld2x4(bufc + 16384 + (dt*32+lo5)*80 + hi*32);
      o[dt] = mfma_mx(vf, P, o[dt]);
    }
    __builtin_amdgcn_s_setprio(0);
    __syncthreads();
  }

  unsigned short* pb = (jh ? pO1 : pO0) + ((size_t)nb*HW_ + q0 + lo5)*C_;
  #pragma unroll
  for(int dt=0;dt<8;dt++){
    #pragma unroll
    for(int g=0;g<4;g++){
      int d0 = dt*32 + g*8 + hi*4;
      unsigned short h0 = f2bf(o[dt][4*g]);
      unsigned short h1 = f2bf(o[dt][4*g+1]);
      unsigned short h2 = f2bf(o[dt][4*g+2]);
      unsigned short h3 = f2bf(o[dt][4*g+3]);
      uint2 uo; uo.x = (unsigned)h0 | ((unsigned)h1<<16);
      uo.y = (unsigned)h2 | ((unsigned)h3<<16);
      *(uint2*)(pb + d0) = uo;
    }
  }
  if (l < 32){
    float2 ml; ml.x = m; ml.y = lsum;
    pml[(size_t)jh*((size_t)N_*HW_) + (size_t)nb*HW_ + q0 + lo5] = ml;
  }
}

extern "C" void kernel_launch(void* const* d_in, const int* in_sizes, int n_in,
                              void* d_out, int out_size, void* d_ws, size_t ws_size,
                              hipStream_t stream) {
  const float* x   = (const float*)d_in[0];
  const float* lnw = (const float*)d_in[1];
  const float* lnb = (const float*)d_in[2];
  const float* wq  = (const float*)d_in[3];
  const float* bq  = (const float*)d_in[4];
  const float* wk  = (const float*)d_in[5];
  const float* bk  = (const float*)d_in[6];
  const float* wv  = (const float*)d_in[7];
  const float* bv  = (const float*)d_in[8];
  const float* wo  = (const float*)d_in[9];
  const float* bo  = (const float*)d_in[10];
  float* out = (float*)d_out;

  uintptr_t base = (uintptr_t)d_ws;
  float2* part  = (float2*)base;                       // 2048 float2
  unsigned short* wqb = (unsigned short*)(base + 16448);
  unsigned short* wkb = wqb + 65536;
  unsigned short* wvb = wqb + 2*65536;
  unsigned short* wob = wqb + 3*65536;
  unsigned short* nx  = wqb + 4*65536;
  const size_t TEN = (size_t)N_*HW_*C_;
  unsigned short* qtb = nx + TEN;       // fp8 Q (8 MB used of 16)
  unsigned short* ktb = qtb + TEN;      // fp8 K
  unsigned short* vvb = ktb + TEN;      // fp8 V [dim][seq]
  unsigned short* pO1 = vvb + TEN;      // bf16 partial O, j-half 1
  float2* pml = (float2*)(pO1 + TEN);   // [2][N*HW] float2
  unsigned short* pO0 = nx;             // alias: nx dead after QKV

  k_cvtall<<<dim3(1024),256,0,stream>>>(wq, wk, wv, wo, wqb);

  k_stats1<<<dim3(2048),256,0,stream>>>(x, part);
  k_norm<<<dim3(64,4,8),256,0,stream>>>(x, lnw, lnb, part, nx);

  // Q,K fp8 scaled by sqrt(log2(e)/16); V fp8 [dim][seq]
  k_gemm2<0,1><<<dim3(32,2,8),256,0,stream>>>(nx, (long)(HW_*C_), wqb, 0L, bq, 0.3002807f,
                                              qtb, (long)(HW_*C_), C_);
  k_gemm2<0,1><<<dim3(32,2,8),256,0,stream>>>(nx, (long)(HW_*C_), wkb, 0L, bk, 0.3002807f,
                                              ktb, (long)(HW_*C_), C_);
  k_gemm2<1,1><<<dim3(2,32,8),256,0,stream>>>(wvb, 0L, nx, (long)(HW_*C_), bv, 1.0f,
                                              vvb, (long)(CNT_), HW_);

  k_attn8<<<dim3(512),256,0,stream>>>((const unsigned char*)qtb, (const unsigned char*)ktb,
                                      (const unsigned char*)vvb, pO0, pO1, pml);

  k_outproj2<<<dim3(2,32,8),256,0,stream>>>(wob, pO0, pO1, pml, bo, x, out);
}

// Round 14
// 150.912 us; speedup vs baseline: 1.7204x; 1.0855x over previous
//
#include <hip/hip_runtime.h>
#include <hip/hip_bf16.h>

#define N_ 8
#define C_ 256
#define HW_ 4096
#define CNT_ (C_*HW_)

typedef __attribute__((ext_vector_type(8))) short bf16x8;
typedef __attribute__((ext_vector_type(4))) float f32x4;
typedef __attribute__((ext_vector_type(16))) float f32x16;
typedef __attribute__((ext_vector_type(4))) int i32x4;
typedef __attribute__((ext_vector_type(8))) int i32x8;

__device__ inline float exp2fast(float x){ return __builtin_amdgcn_exp2f(x); }

__device__ inline unsigned short f2bf(float f){
  union{float f; unsigned u;} v; v.f=f;
  unsigned r = v.u + 0x7fff + ((v.u>>16)&1);
  return (unsigned short)(r>>16);
}
__device__ inline float bf2f(unsigned short h){
  union{unsigned u; float f;} v; v.u = ((unsigned)h)<<16; return v.f;
}

__device__ inline f32x4 mfma16(bf16x8 a, bf16x8 b, f32x4 c){
  return __builtin_amdgcn_mfma_f32_16x16x32_bf16(a,b,c,0,0,0);
}
// MX-scaled fp8 K=64 MFMA, scales = 1.0 (E8M0 127), fmt 0 = fp8 e4m3
__device__ inline f32x16 mfma_mx(i32x8 a, i32x8 b, f32x16 c){
  return __builtin_amdgcn_mfma_scale_f32_32x32x64_f8f6f4(a, b, c, 0, 0, 0, 127, 0, 127);
}

__device__ inline i32x8 ld2x4(const char* p){
  i32x4 a = *(const i32x4*)p;
  i32x4 b = *(const i32x4*)(p+16);
  i32x8 r;
  r[0]=a[0]; r[1]=a[1]; r[2]=a[2]; r[3]=a[3];
  r[4]=b[0]; r[5]=b[1]; r[6]=b[2]; r[7]=b[3];
  return r;
}

#define GLL16(gp, lp) __builtin_amdgcn_global_load_lds( \
    (__attribute__((address_space(1))) void*)(gp), \
    (__attribute__((address_space(3))) void*)(lp), 16, 0, 0)

// ---------------- prologue kernel: weight cvt + bias concat + LN stats stage 1 --------
// blocks 0..1023: weight fp32->bf16 (wq|wk|wv|wo -> contiguous dst)
// block  1024   : bqk[0..255]=bq, bqk[256..511]=bk
// blocks 1025.. : layernorm partial sums (chunk = bid-1025)
__global__ void k_pre(const float* __restrict__ wq, const float* __restrict__ wk,
                      const float* __restrict__ wv, const float* __restrict__ wo,
                      const float* __restrict__ bq, const float* __restrict__ bk,
                      unsigned short* __restrict__ dst, float* __restrict__ bqk,
                      const float* __restrict__ x, float2* __restrict__ part){
  int bid = blockIdx.x, t = threadIdx.x;
  if (bid < 1024){
    int i = bid*256 + t;
    const float* s = (i < 65536) ? wq : (i < 131072) ? wk : (i < 196608) ? wv : wo;
    dst[i] = f2bf(s[i & 65535]);
    return;
  }
  if (bid == 1024){
    bqk[t] = bq[t];
    bqk[256+t] = bk[t];
    return;
  }
  int cid = bid - 1025;
  int n = cid >> 8, chunk = cid & 255;
  const float4* p = (const float4*)(x + (size_t)n*CNT_ + (size_t)chunk*4096);
  float s=0.f, s2=0.f;
  #pragma unroll
  for(int i=0;i<4;i++){
    float4 v = p[t + 256*i];
    s  += v.x+v.y+v.z+v.w;
    s2 += v.x*v.x+v.y*v.y+v.z*v.z+v.w*v.w;
  }
  #pragma unroll
  for(int o=32;o;o>>=1){ s += __shfl_down(s,o); s2 += __shfl_down(s2,o); }
  __shared__ float sh[4], sh2[4];
  int lane = t&63, wid = t>>6;
  if(lane==0){ sh[wid]=s; sh2[wid]=s2; }
  __syncthreads();
  if(t==0){
    float2 r; r.x = sh[0]+sh[1]+sh[2]+sh[3]; r.y = sh2[0]+sh2[1]+sh2[2]+sh2[3];
    part[cid] = r;
  }
}

// ---------------- normalize + transpose to NHWC bf16 (stats stage-2 inlined) ----------------
__global__ void k_norm(const float* __restrict__ x, const float* __restrict__ lnw,
                       const float* __restrict__ lnb, const float2* __restrict__ part,
                       unsigned short* __restrict__ nx){
  __shared__ float tile[64][65];
  __shared__ float2 stsh;
  int n = blockIdx.z, c0 = blockIdx.y*64, p0 = blockIdx.x*64;
  int t = threadIdx.x, col = t&63, rw = t>>6;
  {
    float2 v = part[n*256 + t];
    float s = v.x, s2 = v.y;
    #pragma unroll
    for(int o=32;o;o>>=1){ s += __shfl_down(s,o); s2 += __shfl_down(s2,o); }
    __shared__ float sh[4], sh2[4];
    int lane = t&63, wid = t>>6;
    if(lane==0){ sh[wid]=s; sh2[wid]=s2; }
    __syncthreads();
    if(t==0){
      s = sh[0]+sh[1]+sh[2]+sh[3];
      s2 = sh2[0]+sh2[1]+sh2[2]+sh2[3];
      float mean = s * (1.f/(float)CNT_);
      float var  = s2 * (1.f/(float)CNT_) - mean*mean;
      float2 r; r.x = mean; r.y = rsqrtf(var + 1e-5f);
      stsh = r;
    }
    __syncthreads();
  }
  float mu = stsh.x, rs = stsh.y;
  #pragma unroll
  for(int pass=0; pass<16; pass++){
    int row = pass*4 + rw;
    size_t gi = (size_t)(c0+row)*HW_ + (p0+col);
    float v = x[(size_t)n*CNT_ + gi];
    tile[row][col] = (v - mu)*rs*lnw[gi] + lnb[gi];
  }
  __syncthreads();
  #pragma unroll
  for(int pass=0; pass<16; pass++){
    int prow = pass*4 + rw;
    nx[((size_t)n*HW_ + p0+prow)*C_ + c0 + col] = f2bf(tile[col][prow]);
  }
}

// ---------------- 128x128-tile B^T GEMM, LDS-staged (dbuf, issue-early) ----------------
// OUT_MODE: 0 = bf16, 1 = fp8-e4m3
__device__ inline void g2_stage(const char* A, const char* B, char* buf,
                                int w, int r8, int s8, int i0, int c0, int kb0){
  int sl = (s8 ^ (r8&7)) << 4;
  #pragma unroll
  for(int q=0;q<4;q++){
    int row = w*32 + q*8 + r8;
    GLL16(A + (size_t)(i0+row)*512 + kb0 + sl, buf + w*4096 + q*1024);
    GLL16(B + (size_t)(c0+row)*512 + kb0 + sl, buf + 16384 + w*4096 + q*1024);
  }
}

template<int BIAS_ROW, int OUT_MODE>
__global__ __launch_bounds__(256, 2) void k_gemm2(
    const unsigned short* __restrict__ Ab, long sA,
    const unsigned short* __restrict__ Bb, long sB,
    const float* __restrict__ bias, float scale,
    void* __restrict__ Outb, long sO, int ldo){
  __shared__ __align__(16) char lds[65536];
  int n = blockIdx.z;
  const char* A = (const char*)(Ab + (size_t)n*sA);
  const char* B = (const char*)(Bb + (size_t)n*sB);
  int t = threadIdx.x, w = t>>6, l = t&63;
  int wr = w>>1, wc = w&1, ri = l&15, kq = l>>4;
  int r8 = l>>3, s8 = l&7;
  int i0 = blockIdx.x*128, c0 = blockIdx.y*128;

  f32x4 acc[4][4];
  #pragma unroll
  for(int m=0;m<4;m++)
    #pragma unroll
    for(int nn=0;nn<4;nn++)
      #pragma unroll
      for(int r=0;r<4;r++) acc[m][nn][r] = 0.f;

  g2_stage(A, B, lds, w, r8, s8, i0, c0, 0);
  __syncthreads();

  for(int kt=0; kt<4; ++kt){
    char* buf = lds + (kt&1)*32768;
    if (kt < 3) g2_stage(A, B, lds + ((kt&1)^1)*32768, w, r8, s8, i0, c0, (kt+1)*128);
    __builtin_amdgcn_s_setprio(1);
    #pragma unroll
    for(int kc=0;kc<2;kc++){
      bf16x8 af[4], bfv[4];
      #pragma unroll
      for(int m=0;m<4;m++){
        int row = wr*64 + m*16 + ri;
        af[m] = *(const bf16x8*)(buf + row*128 + ((((kc<<2)|kq) ^ (row&7))<<4));
      }
      #pragma unroll
      for(int nn=0;nn<4;nn++){
        int row = wc*64 + nn*16 + ri;
        bfv[nn] = *(const bf16x8*)(buf + 16384 + row*128 + ((((kc<<2)|kq) ^ (row&7))<<4));
      }
      #pragma unroll
      for(int m=0;m<4;m++)
        #pragma unroll
        for(int nn=0;nn<4;nn++)
          acc[m][nn] = mfma16(af[m], bfv[nn], acc[m][nn]);
    }
    __builtin_amdgcn_s_setprio(0);
    __syncthreads();
  }

  if (OUT_MODE == 1){
    unsigned char* O8 = (unsigned char*)Outb + (size_t)n*sO;
    #pragma unroll
    for(int m=0;m<4;m++){
      #pragma unroll
      for(int nn=0;nn<4;nn++){
        #pragma unroll
        for(int r=0;r<4;r++){
          int row = i0 + wr*64 + m*16 + kq*4 + r;
          int col = c0 + wc*64 + nn*16 + ri;
          float d = (acc[m][nn][r] + bias[BIAS_ROW ? row : col])*scale;
          unsigned u;
          asm("v_cvt_pk_fp8_f32 %0, %1, %2" : "=v"(u) : "v"(d), "v"(0.f));
          O8[(size_t)row*ldo + col] = (unsigned char)(u & 0xff);
        }
      }
    }
  } else {
    unsigned short* O = (unsigned short*)Outb + (size_t)n*sO;
    #pragma unroll
    for(int m=0;m<4;m++){
      #pragma unroll
      for(int nn=0;nn<4;nn++){
        #pragma unroll
        for(int r=0;r<4;r++){
          int row = i0 + wr*64 + m*16 + kq*4 + r;
          int col = c0 + wc*64 + nn*16 + ri;
          float d = (acc[m][nn][r] + bias[BIAS_ROW ? row : col])*scale;
          O[(size_t)row*ldo + col] = f2bf(d);
        }
      }
    }
  }
}

// ---------------- output projection with inline j-half merge + residual ----------------
__global__ __launch_bounds__(256, 2) void k_outproj2(
    const unsigned short* __restrict__ wob,
    const unsigned short* __restrict__ pO0, const unsigned short* __restrict__ pO1,
    const float2* __restrict__ pml,
    const float* __restrict__ bo, const float* __restrict__ x,
    float* __restrict__ out){
  __shared__ __align__(16) char lds[65536];
  int n = blockIdx.z;
  const char* A = (const char*)wob;
  const char* B0 = (const char*)(pO0 + (size_t)n*HW_*C_);
  const char* B1 = (const char*)(pO1 + (size_t)n*HW_*C_);
  int t = threadIdx.x, w = t>>6, l = t&63;
  int wr = w>>1, wc = w&1, ri = l&15, kq = l>>4;
  int r8 = l>>3, s8 = l&7;
  int i0 = blockIdx.x*128, c0 = blockIdx.y*128;
  int sl = (s8 ^ (r8&7)) << 4;

  float s0v[4], s1v[4];
  #pragma unroll
  for(int q=0;q<4;q++){
    int row = c0 + w*32 + q*8 + r8;
    float2 ml0 = pml[(size_t)n*HW_ + row];
    float2 ml1 = pml[(size_t)N_*HW_ + (size_t)n*HW_ + row];
    float mN = fmaxf(ml0.x, ml1.x);
    float a0 = exp2fast(ml0.x - mN), a1 = exp2fast(ml1.x - mN);
    float inv = 1.f/(a0*ml0.y + a1*ml1.y);
    s0v[q] = a0*inv; s1v[q] = a1*inv;
  }

  f32x4 acc[4][4];
  #pragma unroll
  for(int m=0;m<4;m++)
    #pragma unroll
    for(int nn=0;nn<4;nn++)
      #pragma unroll
      for(int r=0;r<4;r++) acc[m][nn][r] = 0.f;

  uint4 bl0[4], bl1[4];
  #pragma unroll
  for(int q=0;q<4;q++){
    int row = w*32 + q*8 + r8;
    GLL16(A + (size_t)(i0+row)*512 + sl, lds + w*4096 + q*1024);
    bl0[q] = *(const uint4*)(B0 + (size_t)(c0+row)*512 + sl);
    bl1[q] = *(const uint4*)(B1 + (size_t)(c0+row)*512 + sl);
  }
  #pragma unroll
  for(int q=0;q<4;q++){
    unsigned w0[4] = {bl0[q].x, bl0[q].y, bl0[q].z, bl0[q].w};
    unsigned w1[4] = {bl1[q].x, bl1[q].y, bl1[q].z, bl1[q].w};
    unsigned rr[4];
    #pragma unroll
    for(int j=0;j<4;j++){
      float lo = s0v[q]*bf2f((unsigned short)(w0[j]&0xffff)) + s1v[q]*bf2f((unsigned short)(w1[j]&0xffff));
      float hi = s0v[q]*bf2f((unsigned short)(w0[j]>>16))    + s1v[q]*bf2f((unsigned short)(w1[j]>>16));
      rr[j] = (unsigned)f2bf(lo) | ((unsigned)f2bf(hi)<<16);
    }
    uint4 rw; rw.x=rr[0]; rw.y=rr[1]; rw.z=rr[2]; rw.w=rr[3];
    *(uint4*)(lds + 16384 + w*4096 + q*1024 + l*16) = rw;
  }
  __syncthreads();

  for(int kt=0; kt<4; ++kt){
    char* buf  = lds + (kt&1)*32768;
    char* nbuf = lds + ((kt&1)^1)*32768;
    if (kt < 3){
      int kb0 = (kt+1)*128;
      #pragma unroll
      for(int q=0;q<4;q++){
        int row = w*32 + q*8 + r8;
        GLL16(A + (size_t)(i0+row)*512 + kb0 + sl, nbuf + w*4096 + q*1024);
        bl0[q] = *(const uint4*)(B0 + (size_t)(c0+row)*512 + kb0 + sl);
        bl1[q] = *(const uint4*)(B1 + (size_t)(c0+row)*512 + kb0 + sl);
      }
    }
    __builtin_amdgcn_s_setprio(1);
    #pragma unroll
    for(int kc=0;kc<2;kc++){
      bf16x8 af[4], bfv[4];
      #pragma unroll
      for(int m=0;m<4;m++){
        int row = wr*64 + m*16 + ri;
        af[m] = *(const bf16x8*)(buf + row*128 + ((((kc<<2)|kq) ^ (row&7))<<4));
      }
      #pragma unroll
      for(int nn=0;nn<4;nn++){
        int row = wc*64 + nn*16 + ri;
        bfv[nn] = *(const bf16x8*)(buf + 16384 + row*128 + ((((kc<<2)|kq) ^ (row&7))<<4));
      }
      #pragma unroll
      for(int m=0;m<4;m++)
        #pragma unroll
        for(int nn=0;nn<4;nn++)
          acc[m][nn] = mfma16(af[m], bfv[nn], acc[m][nn]);
    }
    __builtin_amdgcn_s_setprio(0);
    if (kt < 3){
      #pragma unroll
      for(int q=0;q<4;q++){
        unsigned w0[4] = {bl0[q].x, bl0[q].y, bl0[q].z, bl0[q].w};
        unsigned w1[4] = {bl1[q].x, bl1[q].y, bl1[q].z, bl1[q].w};
        unsigned rr[4];
        #pragma unroll
        for(int j=0;j<4;j++){
          float lo = s0v[q]*bf2f((unsigned short)(w0[j]&0xffff)) + s1v[q]*bf2f((unsigned short)(w1[j]&0xffff));
          float hi = s0v[q]*bf2f((unsigned short)(w0[j]>>16))    + s1v[q]*bf2f((unsigned short)(w1[j]>>16));
          rr[j] = (unsigned)f2bf(lo) | ((unsigned)f2bf(hi)<<16);
        }
        uint4 rw; rw.x=rr[0]; rw.y=rr[1]; rw.z=rr[2]; rw.w=rr[3];
        *(uint4*)(nbuf + 16384 + w*4096 + q*1024 + l*16) = rw;
      }
    }
    __syncthreads();
  }

  const float* xr = x + (size_t)n*CNT_;
  float* fout = out + (size_t)n*CNT_;
  #pragma unroll
  for(int m=0;m<4;m++){
    #pragma unroll
    for(int nn=0;nn<4;nn++){
      #pragma unroll
      for(int r=0;r<4;r++){
        int row = i0 + wr*64 + m*16 + kq*4 + r;
        int col = c0 + wc*64 + nn*16 + ri;
        size_t idx = (size_t)row*HW_ + col;
        fout[idx] = acc[m][nn][r] + bo[row] + xr[idx];
      }
    }
  }
}

// ---------------- flash attention: all-fp8 MX (K=64), Q/K interleaved at stride 512 -----
// qk8 layout: [seq][512] fp8; Q = cols 0-255, K = cols 256-511.
__device__ inline void stage_KV_mx(const char* kb, const char* vb, char* buf,
                                   int w, int l, int j0){
  #pragma unroll
  for(int k=0;k<4;k++){
    int g = w*4 + k;
    int row = g*4 + (l>>4);
    int i = l & 15;
    int sp = (((i>>1) ^ (row&7))<<5) + ((i&1)<<4);
    GLL16(kb + (size_t)(j0+row)*512 + sp, buf + g*1024);
  }
  #pragma unroll
  for(int k=0;k<5;k++){
    int g = w*5 + k;
    int c = g*64 + l;
    int d = c/5; int sg = c - d*5; sg = (sg==4)?0:sg;
    GLL16(vb + (size_t)d*HW_ + j0 + sg*16, buf + 16384 + g*1024);
  }
}

__global__ __launch_bounds__(256, 2) void k_attn8(const unsigned char* __restrict__ qk8,
                                                  const unsigned char* __restrict__ vv,
                                                  unsigned short* __restrict__ pO0,
                                                  unsigned short* __restrict__ pO1,
                                                  float2* __restrict__ pml){
  __shared__ __align__(16) char lds[73728];     // 2 x (16 KB K + 20 KB V)
  int t = threadIdx.x, w = t>>6, l = t&63, hi = l>>5, lo5 = l&31;
  int nb = blockIdx.x & 7, rem = blockIdx.x >> 3;
  int qb = rem >> 1, jh = rem & 1;
  int q0 = qb*128 + w*32;
  const char* qp = (const char*)(qk8 + (size_t)nb*HW_*512);
  const char* kb = qp + 256;           // K columns
  const char* vb = (const char*)(vv + (size_t)nb*(size_t)CNT_);
  int jbase = jh*2048;

  i32x8 qfr[4];
  #pragma unroll
  for(int db=0; db<4; db++)
    qfr[db] = ld2x4(qp + (size_t)(q0+lo5)*512 + db*64 + hi*32);

  f32x16 o[8];
  #pragma unroll
  for(int dt=0;dt<8;dt++){
    #pragma unroll
    for(int r=0;r<16;r++) o[dt][r]=0.f;
  }
  float m = -1e30f, lsum = 0.f;

  stage_KV_mx(kb, vb, lds, w, l, jbase);
  __syncthreads();

  for(int it=0; it<32; ++it){
    char* bufc = lds + (it&1)*36864;
    if (it < 31) stage_KV_mx(kb, vb, lds + ((it&1)^1)*36864, w, l, jbase + (it+1)*64);

    f32x16 Sa, Sb;
    #pragma unroll
    for(int r=0;r<16;r++){ Sa[r]=0.f; Sb[r]=0.f; }
    __builtin_amdgcn_s_setprio(1);
    #pragma unroll
    for(int db=0; db<4; db++){
      int sl = ((db*2+hi) ^ (lo5&7))<<5;
      i32x8 ka  = ld2x4(bufc + lo5*256      + sl);
      i32x8 kb2 = ld2x4(bufc + (32+lo5)*256 + sl);
      Sa = mfma_mx(ka,  qfr[db], Sa);
      Sb = mfma_mx(kb2, qfr[db], Sb);
    }
    __builtin_amdgcn_s_setprio(0);

    float mm[8];
    #pragma unroll
    for(int r=0;r<8;r++) mm[r] = fmaxf(fmaxf(Sa[r],Sa[r+8]), fmaxf(Sb[r],Sb[r+8]));
    mm[0]=fmaxf(mm[0],mm[4]); mm[1]=fmaxf(mm[1],mm[5]);
    mm[2]=fmaxf(mm[2],mm[6]); mm[3]=fmaxf(mm[3],mm[7]);
    float mx = fmaxf(fmaxf(mm[0],mm[1]), fmaxf(mm[2],mm[3]));
    { float mA = mx, mB = mx;
      asm("v_permlane32_swap_b32 %0, %1" : "+v"(mA), "+v"(mB));
      mx = fmaxf(mA, mB); }
    if (!__all(mx <= m + 8.f)){     // THR=8: P <= 256 < fp8 e4m3 max 448
      float mn = fmaxf(m, mx);
      float al = exp2fast(m - mn);
      lsum *= al;
      #pragma unroll
      for(int dt=0;dt<8;dt++) o[dt] = o[dt] * al;
      m = mn;
    }
    float rs = 0.f;
    #pragma unroll
    for(int r=0;r<16;r++){
      Sa[r] = exp2fast(Sa[r]-m); rs += Sa[r];
      Sb[r] = exp2fast(Sb[r]-m); rs += Sb[r];
    }
    { float rA = rs, rB = rs;
      asm("v_permlane32_swap_b32 %0, %1" : "+v"(rA), "+v"(rB));
      lsum += rA + rB; }

    unsigned Aw[4], Bw[4];
    #pragma unroll
    for(int w4=0; w4<4; w4++){
      unsigned ua, ub;
      asm("v_cvt_pk_fp8_f32 %0, %1, %2" : "=v"(ua) : "v"(Sa[4*w4]), "v"(Sa[4*w4+1]));
      asm("v_cvt_pk_fp8_f32 %0, %1, %2 op_sel:[0,0,1]" : "+v"(ua) : "v"(Sa[4*w4+2]), "v"(Sa[4*w4+3]));
      asm("v_cvt_pk_fp8_f32 %0, %1, %2" : "=v"(ub) : "v"(Sb[4*w4]), "v"(Sb[4*w4+1]));
      asm("v_cvt_pk_fp8_f32 %0, %1, %2 op_sel:[0,0,1]" : "+v"(ub) : "v"(Sb[4*w4+2]), "v"(Sb[4*w4+3]));
      Aw[w4] = ua; Bw[w4] = ub;
    }
    #pragma unroll
    for(int w4=0; w4<4; w4++)
      asm("v_permlane32_swap_b32 %0, %1" : "+v"(Aw[w4]), "+v"(Bw[w4]));
    i32x8 P;
    P[0]=Aw[0]; P[1]=Bw[0]; P[2]=Aw[1]; P[3]=Bw[1];
    P[4]=Aw[2]; P[5]=Bw[2]; P[6]=Aw[3]; P[7]=Bw[3];

    __builtin_amdgcn_s_setprio(1);
    #pragma unroll
    for(int dt=0;dt<8;dt++){
      i32x8 vf = ld2x4(bufc + 16384 + (dt*32+lo5)*80 + hi*32);
      o[dt] = mfma_mx(vf, P, o[dt]);
    }
    __builtin_amdgcn_s_setprio(0);
    __syncthreads();
  }

  unsigned short* pb = (jh ? pO1 : pO0) + ((size_t)nb*HW_ + q0 + lo5)*C_;
  #pragma unroll
  for(int dt=0;dt<8;dt++){
    #pragma unroll
    for(int g=0;g<4;g++){
      int d0 = dt*32 + g*8 + hi*4;
      unsigned short h0 = f2bf(o[dt][4*g]);
      unsigned short h1 = f2bf(o[dt][4*g+1]);
      unsigned short h2 = f2bf(o[dt][4*g+2]);
      unsigned short h3 = f2bf(o[dt][4*g+3]);
      uint2 uo; uo.x = (unsigned)h0 | ((unsigned)h1<<16);
      uo.y = (unsigned)h2 | ((unsigned)h3<<16);
      *(uint2*)(pb + d0) = uo;
    }
  }
  if (l < 32){
    float2 ml; ml.x = m; ml.y = lsum;
    pml[(size_t)jh*((size_t)N_*HW_) + (size_t)nb*HW_ + q0 + lo5] = ml;
  }
}

extern "C" void kernel_launch(void* const* d_in, const int* in_sizes, int n_in,
                              void* d_out, int out_size, void* d_ws, size_t ws_size,
                              hipStream_t stream) {
  const float* x   = (const float*)d_in[0];
  const float* lnw = (const float*)d_in[1];
  const float* lnb = (const float*)d_in[2];
  const float* wq  = (const float*)d_in[3];
  const float* bq  = (const float*)d_in[4];
  const float* wk  = (const float*)d_in[5];
  const float* bk  = (const float*)d_in[6];
  const float* wv  = (const float*)d_in[7];
  const float* bv  = (const float*)d_in[8];
  const float* wo  = (const float*)d_in[9];
  const float* bo  = (const float*)d_in[10];
  float* out = (float*)d_out;

  uintptr_t base = (uintptr_t)d_ws;
  float2* part  = (float2*)base;                       // 2048 float2 (16 KB)
  float*  bqk   = (float*)(base + 16384);              // 512 floats
  unsigned short* wqb = (unsigned short*)(base + 18432);
  unsigned short* wkb = wqb + 65536;                   // contiguous -> wqk = wqb (512x256)
  unsigned short* wvb = wqb + 2*65536;
  unsigned short* wob = wqb + 3*65536;
  unsigned short* nx  = wqb + 4*65536;
  const size_t TEN = (size_t)N_*HW_*C_;
  unsigned short* qkb = nx + TEN;       // fp8 QK [seq][512] = 16.8 MB (fills this region)
  unsigned short* vvb = qkb + TEN;      // fp8 V [dim][seq]
  unsigned short* pO1 = vvb + TEN;      // bf16 partial O, j-half 1
  float2* pml = (float2*)(pO1 + TEN);   // [2][N*HW] float2
  unsigned short* pO0 = nx;             // alias: nx dead after QKV
  (void)wkb;

  k_pre<<<dim3(3073),256,0,stream>>>(wq, wk, wv, wo, bq, bk, wqb, bqk, x, part);
  k_norm<<<dim3(64,4,8),256,0,stream>>>(x, lnw, lnb, part, nx);

  // QK fused: B = [wq;wk] (512 rows), out fp8 [seq][512]; scale sqrt(log2e/16)
  k_gemm2<0,1><<<dim3(32,4,8),256,0,stream>>>(nx, (long)(HW_*C_), wqb, 0L, bqk, 0.3002807f,
                                              qkb, (long)(HW_*512), 512);
  // V: fp8 [dim][seq]
  k_gemm2<1,1><<<dim3(2,32,8),256,0,stream>>>(wvb, 0L, nx, (long)(HW_*C_), bv, 1.0f,
                                              vvb, (long)(CNT_), HW_);

  k_attn8<<<dim3(512),256,0,stream>>>((const unsigned char*)qkb,
                                      (const unsigned char*)vvb, pO0, pO1, pml);

  k_outproj2<<<dim3(2,32,8),256,0,stream>>>(wob, pO0, pO1, pml, bo, x, out);
}